// Round 2
// baseline (854.774 us; speedup 1.0000x reference)
//
#include <hip/hip_runtime.h>
#include <hip/hip_bf16.h>

// MambaFeatureEnhancer — B=2, C=128, H=W=64 -> L=4096, d_inner=256, N=16, R=8, 2 layers.
// All device inputs/outputs are FLOAT32 (npz-size evidence). Intermediates fp32 in d_ws (~55 MB).

#define LSEQ 4096
#define BLC  8192      // B * L
#define NC   32        // scan chunks
#define CHK  128       // chunk length (NC*CHK = LSEQ)

// ---------------------------------------------------------------- transpose
// per batch: in (R x Cc) -> out (Cc x R); optional residual add (indexed as out)
template<bool ADD>
__global__ __launch_bounds__(256) void transpose_kernel(
    const float* __restrict__ in_, float* __restrict__ out_,
    const float* __restrict__ add, int R, int Cc)
{
    __shared__ float tile[32][33];
    size_t boff = (size_t)blockIdx.z * R * Cc;
    int r0 = blockIdx.y * 32, c0 = blockIdx.x * 32;
    int tx = threadIdx.x, ty = threadIdx.y;   // block (32,8)
#pragma unroll
    for (int j = 0; j < 4; ++j) {
        size_t idx = boff + (size_t)(r0 + ty + j * 8) * Cc + (c0 + tx);
        tile[ty + j * 8][tx] = in_[idx];
    }
    __syncthreads();
#pragma unroll
    for (int j = 0; j < 4; ++j) {
        size_t idx = boff + (size_t)(c0 + ty + j * 8) * R + (r0 + tx);
        float v = tile[tx][ty + j * 8];
        if (ADD) v += add[idx];
        out_[idx] = v;
    }
}

// ---------------------------------------------------------------- GEMM
// Y[m,n] = act( sum_k X[m,k]*W[n,k] + bias[n] ) + res[m,n]
// X fp32 row-major (lda), W/bias fp32 (N x K row-major), Y fp32 (row stride N).
// M is always 8192 (grid.x * 64). ACT: 0 none, 1 softplus, 2 gelu(exact).
template<int ACT, bool BIAS, bool RES>
__global__ __launch_bounds__(256) void gemm_kernel(
    const float* __restrict__ X, int lda,
    const float* __restrict__ W,
    const float* __restrict__ bias,
    const float* __restrict__ res,
    float* __restrict__ Y, int N, int K)
{
    __shared__ __align__(16) float As[16][68];
    __shared__ __align__(16) float Ws[16][68];
    int bm = blockIdx.x * 64;
    int bn = blockIdx.y * 64;
    int tid = threadIdx.x;
    int tm = (tid >> 4) << 2;     // 0..60
    int tn = (tid & 15) << 2;     // 0..60
    float acc[4][4] = {};

    for (int k0 = 0; k0 < K; k0 += 16) {
#pragma unroll
        for (int i = 0; i < 4; ++i) {
            int idx = tid + i * 256;       // 0..1023
            int m  = idx >> 4;
            int kk = idx & 15;
            int gk = k0 + kk;
            As[kk][m] = (gk < K) ? X[(size_t)(bm + m) * lda + gk] : 0.f;
            int gn = bn + m;
            Ws[kk][m] = (gk < K && gn < N) ? W[(size_t)gn * K + gk] : 0.f;
        }
        __syncthreads();
#pragma unroll
        for (int kk = 0; kk < 16; ++kk) {
            float4 av = *reinterpret_cast<const float4*>(&As[kk][tm]);
            float4 bv = *reinterpret_cast<const float4*>(&Ws[kk][tn]);
            float a[4] = {av.x, av.y, av.z, av.w};
            float b[4] = {bv.x, bv.y, bv.z, bv.w};
#pragma unroll
            for (int i2 = 0; i2 < 4; ++i2)
#pragma unroll
                for (int j2 = 0; j2 < 4; ++j2)
                    acc[i2][j2] = fmaf(a[i2], b[j2], acc[i2][j2]);
        }
        __syncthreads();
    }

#pragma unroll
    for (int i2 = 0; i2 < 4; ++i2) {
        int gm = bm + tm + i2;
#pragma unroll
        for (int j2 = 0; j2 < 4; ++j2) {
            int gn = bn + tn + j2;
            if (gn < N) {
                float v = acc[i2][j2];
                if (BIAS) v += bias[gn];
                if (ACT == 1) {                       // softplus
                    v = (v > 0.f) ? v + log1pf(expf(-v)) : log1pf(expf(v));
                } else if (ACT == 2) {                // exact gelu
                    v = 0.5f * v * (1.f + erff(v * 0.70710678118654752f));
                }
                size_t o = (size_t)gm * N + gn;
                if (RES) v += res[o];
                Y[o] = v;
            }
        }
    }
}

// ---------------------------------------------------------------- layernorm
// rows = 8192, 128 cols; one wave per row.
__global__ __launch_bounds__(256) void ln_kernel(
    const float* __restrict__ X, const float* __restrict__ g,
    const float* __restrict__ bb, float* __restrict__ Y)
{
    int row  = blockIdx.x * 4 + (threadIdx.x >> 6);
    int lane = threadIdx.x & 63;
    const float* xr = X + (size_t)row * 128;
    float v0 = xr[lane], v1 = xr[lane + 64];
    float s = v0 + v1;
#pragma unroll
    for (int off = 32; off > 0; off >>= 1) s += __shfl_xor(s, off, 64);
    float mean = s * 0.0078125f;
    float d0 = v0 - mean, d1 = v1 - mean;
    float q = d0 * d0 + d1 * d1;
#pragma unroll
    for (int off = 32; off > 0; off >>= 1) q += __shfl_xor(q, off, 64);
    float rstd = rsqrtf(q * 0.0078125f + 1e-5f);
    float* yr = Y + (size_t)row * 128;
    yr[lane]      = d0 * rstd * g[lane]      + bb[lane];
    yr[lane + 64] = d1 * rstd * g[lane + 64] + bb[lane + 64];
}

// ---------------------------------------------------------------- conv1d (depthwise, causal, k=4) + silu
// u = xz[:, 0:256]; out (BLC x 256)
__global__ __launch_bounds__(256) void conv_silu_kernel(
    const float* __restrict__ xz, const float* __restrict__ cw,
    const float* __restrict__ cb, float* __restrict__ out)
{
    int i   = blockIdx.x * 256 + threadIdx.x;   // over BLC*256
    int d   = i & 255;
    int row = i >> 8;
    int l   = row & (LSEQ - 1);
    float v = cb[d];
    float w0 = cw[d * 4], w1 = cw[d * 4 + 1];
    float w2 = cw[d * 4 + 2], w3 = cw[d * 4 + 3];
    const float* base = xz + (size_t)row * 512 + d;
    if (l >= 3) {
        v += base[-3 * 512] * w0 + base[-2 * 512] * w1 + base[-512] * w2 + base[0] * w3;
    } else {
        if (l >= 2) v += base[-2 * 512] * w1;
        if (l >= 1) v += base[-1 * 512] * w2;
        v += base[0] * w3;
    }
    float sig = 1.f / (1.f + expf(-v));
    out[i] = v * sig;
}

// ---------------------------------------------------------------- chunked selective scan
// idx = (((b*256+d)*NC)+c)*16+n  -> lane group of 16 = n, 4 chunks per wave.
// Phase 1: per-chunk h (h0=0) and prod(a).
__global__ __launch_bounds__(256) void scan_phase1(
    const float* __restrict__ dtb, const float* __restrict__ ucv,
    const float* __restrict__ dbl, const float* __restrict__ A_log,
    float* __restrict__ hend, float* __restrict__ aprod)
{
    int idx = blockIdx.x * 256 + threadIdx.x;
    int n = idx & 15;
    int c = (idx >> 4) & 31;
    int d = (idx >> 9) & 255;
    int b = idx >> 17;
    float An = -expf(A_log[d * 16 + n]);
    float h = 0.f, ap = 1.f;
    int row0 = b * LSEQ + c * CHK;
#pragma unroll 4
    for (int t = 0; t < CHK; ++t) {
        int row = row0 + t;
        float dtv = dtb[(size_t)row * 256 + d];
        float uv  = ucv[(size_t)row * 256 + d];
        float bm  = dbl[(size_t)row * 40 + 8 + n];
        float a = __expf(dtv * An);
        h = fmaf(a, h, dtv * uv * bm);
        ap *= a;
    }
    int ch = (b * 256 + d) * 16 + n;
    hend [ch * NC + c] = h;
    aprod[ch * NC + c] = ap;
}

// Phase 2: serial prefix over the 32 chunks of each of the 8192 channels (x16 n) -> h0 per chunk.
__global__ __launch_bounds__(256) void scan_phase2(
    const float* __restrict__ hend, const float* __restrict__ aprod,
    float* __restrict__ h0)
{
    int ch = blockIdx.x * 256 + threadIdx.x;   // 8192*16 channel-state pairs / 16... (131072 total)
    float h = 0.f;
#pragma unroll
    for (int c = 0; c < NC; ++c) {
        h0[ch * NC + c] = h;
        h = fmaf(aprod[ch * NC + c], h, hend[ch * NC + c]);
    }
}

// Phase 3: recompute chunk from correct h0, reduce over n, fuse +u*D and *silu(z).
__global__ __launch_bounds__(256) void scan_phase3(
    const float* __restrict__ dtb, const float* __restrict__ ucv,
    const float* __restrict__ dbl, const float* __restrict__ xz,
    const float* __restrict__ A_log, const float* __restrict__ Dp,
    const float* __restrict__ h0, float* __restrict__ y)
{
    int idx = blockIdx.x * 256 + threadIdx.x;
    int n = idx & 15;
    int c = (idx >> 4) & 31;
    int d = (idx >> 9) & 255;
    int b = idx >> 17;
    float An = -expf(A_log[d * 16 + n]);
    float Dd = Dp[d];
    int ch = (b * 256 + d) * 16 + n;
    float h = h0[ch * NC + c];
    int row0 = b * LSEQ + c * CHK;
#pragma unroll 4
    for (int t = 0; t < CHK; ++t) {
        int row = row0 + t;
        float dtv = dtb[(size_t)row * 256 + d];
        float uv  = ucv[(size_t)row * 256 + d];
        float bm  = dbl[(size_t)row * 40 + 8 + n];
        float cm  = dbl[(size_t)row * 40 + 24 + n];
        float a = __expf(dtv * An);
        h = fmaf(a, h, dtv * uv * bm);
        float p = h * cm;
        p += __shfl_xor(p, 8, 16);
        p += __shfl_xor(p, 4, 16);
        p += __shfl_xor(p, 2, 16);
        p += __shfl_xor(p, 1, 16);
        if (n == 0) {
            float zv = xz[(size_t)row * 512 + 256 + d];
            float sil = zv / (1.f + expf(-zv));
            y[(size_t)row * 256 + d] = (p + uv * Dd) * sil;
        }
    }
}

// ---------------------------------------------------------------- launch
extern "C" void kernel_launch(void* const* d_in, const int* in_sizes, int n_in,
                              void* d_out, int out_size, void* d_ws, size_t ws_size,
                              hipStream_t stream)
{
    const float* x        = (const float*)d_in[0];
    const float* embed_w  = (const float*)d_in[1];
    const float* embed_b  = (const float*)d_in[2];
    const float* outc_w   = (const float*)d_in[3];
    const float* outc_b   = (const float*)d_in[4];
    const float* ln_g     = (const float*)d_in[5];
    const float* ln_b     = (const float*)d_in[6];
    const float* in_w     = (const float*)d_in[7];
    const float* conv_w   = (const float*)d_in[8];
    const float* conv_b   = (const float*)d_in[9];
    const float* xproj_w  = (const float*)d_in[10];
    const float* dtproj_w = (const float*)d_in[11];
    const float* dtproj_b = (const float*)d_in[12];
    const float* A_log    = (const float*)d_in[13];
    const float* ssm_D    = (const float*)d_in[14];
    const float* mout_w   = (const float*)d_in[15];
    const float* ffn_w1   = (const float*)d_in[16];
    const float* ffn_b1   = (const float*)d_in[17];
    const float* ffn_w2   = (const float*)d_in[18];
    const float* ffn_b2   = (const float*)d_in[19];

    float* ws  = (float*)d_ws;
    float* t    = ws;                  // (BLC,128)
    float* t2   = ws + 1048576;        // (BLC,128)
    float* xzb  = ws + 2097152;        // (BLC,512) — also FFN mid
    float* ucv  = ws + 6291456;        // (BLC,256)
    float* dtb  = ws + 8388608;        // (BLC,256)
    float* ym   = ws + 10485760;       // (BLC,256)
    float* dbl  = ws + 12582912;       // (BLC,40)
    float* hend = ws + 12910592;       // 8192*16*32... (131072*32? no: 8192ch*16n -> see below)
    float* apr  = ws + 13172736;
    float* h0b  = ws + 13434880;       // (total 13,697,024 floats ≈ 55 MB)
    float* out = (float*)d_out;

    dim3 tb(32, 8);
    // x (B,C,L) -> t2 (B,L,C)
    transpose_kernel<false><<<dim3(128, 4, 2), tb, 0, stream>>>(x, t2, nullptr, 128, 4096);
    // embed
    gemm_kernel<0, true, false><<<dim3(128, 2), 256, 0, stream>>>(t2, 128, embed_w, embed_b, nullptr, t, 128, 128);

    for (int i = 0; i < 2; ++i) {
        ln_kernel<<<2048, 256, 0, stream>>>(t, ln_g + i * 128, ln_b + i * 128, t2);
        gemm_kernel<0, false, false><<<dim3(128, 8), 256, 0, stream>>>(t2, 128, in_w + i * 65536, nullptr, nullptr, xzb, 512, 128);
        conv_silu_kernel<<<8192, 256, 0, stream>>>(xzb, conv_w + i * 1024, conv_b + i * 256, ucv);
        gemm_kernel<0, false, false><<<dim3(128, 1), 256, 0, stream>>>(ucv, 256, xproj_w + i * 10240, nullptr, nullptr, dbl, 40, 256);
        gemm_kernel<1, true, false><<<dim3(128, 4), 256, 0, stream>>>(dbl, 40, dtproj_w + i * 2048, dtproj_b + i * 256, nullptr, dtb, 256, 8);
        scan_phase1<<<1024, 256, 0, stream>>>(dtb, ucv, dbl, A_log + i * 4096, hend, apr);
        scan_phase2<<<512, 256, 0, stream>>>(hend, apr, h0b);
        scan_phase3<<<1024, 256, 0, stream>>>(dtb, ucv, dbl, xzb, A_log + i * 4096, ssm_D + i * 256, h0b, ym);
        gemm_kernel<0, false, true><<<dim3(128, 2), 256, 0, stream>>>(ym, 256, mout_w + i * 32768, nullptr, t, t, 128, 256);
        ln_kernel<<<2048, 256, 0, stream>>>(t, ln_g + i * 128, ln_b + i * 128, t2);
        gemm_kernel<2, true, false><<<dim3(128, 8), 256, 0, stream>>>(t2, 128, ffn_w1 + i * 65536, ffn_b1 + i * 512, nullptr, xzb, 512, 128);
        gemm_kernel<0, true, true><<<dim3(128, 2), 256, 0, stream>>>(xzb, 512, ffn_w2 + i * 65536, ffn_b2 + i * 128, t, t, 128, 512);
    }

    gemm_kernel<0, true, false><<<dim3(128, 2), 256, 0, stream>>>(t, 128, outc_w, outc_b, nullptr, t2, 128, 128);
    // t2 (B,L,C) -> out (B,C,L) + residual x
    transpose_kernel<true><<<dim3(4, 128, 2), tb, 0, stream>>>(t2, out, x, 4096, 128);
}

// Round 4
// 570.394 us; speedup vs baseline: 1.4986x; 1.4986x over previous
//
#include <hip/hip_runtime.h>
#include <hip/hip_bf16.h>

// MambaFeatureEnhancer — B=2, C=128, L=4096, d_inner=256, N=16, R=8, 2 layers. All I/O fp32.
// Big GEMMs: bf16 MFMA (fp32 accum). dt path (xproj/dtproj) + scan stay fp32.
// Workspace budget: 12,386,304 floats = 49.5 MB (round-2 proven bound was 54.8 MB).

#define LSEQ 4096
#define BLC  8192      // B * L
#define NC   32        // scan chunks
#define CHK  128       // chunk length
#define NCH  8192      // B * d_inner * N state channels

typedef __attribute__((ext_vector_type(4))) float f32x4;
typedef __attribute__((ext_vector_type(8))) short s16x8;

__device__ __forceinline__ unsigned short f2bu(float f) {   // fp32 -> bf16 bits, RNE
    unsigned u = __float_as_uint(f);
    return (unsigned short)((u + 0x7fffu + ((u >> 16) & 1u)) >> 16);
}

// ---------------------------------------------------------------- transpose
template<bool ADD>
__global__ __launch_bounds__(256) void transpose_kernel(
    const float* __restrict__ in_, float* __restrict__ out_,
    const float* __restrict__ add, int R, int Cc)
{
    __shared__ float tile[32][33];
    size_t boff = (size_t)blockIdx.z * R * Cc;
    int r0 = blockIdx.y * 32, c0 = blockIdx.x * 32;
    int tx = threadIdx.x, ty = threadIdx.y;   // block (32,8)
#pragma unroll
    for (int j = 0; j < 4; ++j)
        tile[ty + j * 8][tx] = in_[boff + (size_t)(r0 + ty + j * 8) * Cc + (c0 + tx)];
    __syncthreads();
#pragma unroll
    for (int j = 0; j < 4; ++j) {
        size_t idx = boff + (size_t)(c0 + ty + j * 8) * R + (r0 + tx);
        float v = tile[tx][ty + j * 8];
        if (ADD) v += add[idx];
        out_[idx] = v;
    }
}

// ---------------------------------------------------------------- bf16 MFMA GEMM
// Y[m,n] = act( sum_k X[m,k]*W[n,k] + bias[n] ) (+ res[m,n])
// X fp32 (M x K, stride K), W fp32 (N x K), Y fp32 (stride N). M=8192.
// Tiles: BM=128, BN=64, BK=64. 256 threads = 4 waves (2x2). K,N multiples of 64.
template<int ACT, bool BIAS, bool RES>
__global__ __launch_bounds__(256) void mgemm(
    const float* __restrict__ X, const float* __restrict__ W,
    const float* __restrict__ bias, const float* __restrict__ res,
    float* __restrict__ Y, int N, int K)
{
    __shared__ __align__(16) unsigned short Xs[128 * 64];
    __shared__ __align__(16) unsigned short Ws[64 * 64];
    int tid  = threadIdx.x;
    int lane = tid & 63;
    int wave = tid >> 6;
    int wm = wave >> 1, wn = wave & 1;
    int l15 = lane & 15, l4 = lane >> 4;
    int bm = blockIdx.x * 128, bn = blockIdx.y * 64;
    f32x4 acc[4][2] = {};

    int q  = tid & 15;     // col-quad (4 floats)
    int r0 = tid >> 4;     // 0..15

    for (int k0 = 0; k0 < K; k0 += 64) {
        __syncthreads();
#pragma unroll
        for (int p = 0; p < 8; ++p) {                       // stage X: 128x64
            int row = r0 + p * 16;
            float4 v = *(const float4*)&X[(size_t)(bm + row) * K + k0 + q * 4];
            unsigned lo = f2bu(v.x) | ((unsigned)f2bu(v.y) << 16);
            unsigned hi = f2bu(v.z) | ((unsigned)f2bu(v.w) << 16);
            int off = (row * 128 + q * 8) ^ ((row & 7) << 4);
            *(uint2*)((char*)Xs + off) = make_uint2(lo, hi);
        }
#pragma unroll
        for (int p = 0; p < 4; ++p) {                       // stage W: 64x64
            int row = r0 + p * 16;
            float4 v = *(const float4*)&W[(size_t)(bn + row) * K + k0 + q * 4];
            unsigned lo = f2bu(v.x) | ((unsigned)f2bu(v.y) << 16);
            unsigned hi = f2bu(v.z) | ((unsigned)f2bu(v.w) << 16);
            int off = (row * 128 + q * 8) ^ ((row & 7) << 4);
            *(uint2*)((char*)Ws + off) = make_uint2(lo, hi);
        }
        __syncthreads();
#pragma unroll
        for (int ks = 0; ks < 2; ++ks) {
            s16x8 a[4], b[2];
#pragma unroll
            for (int mf = 0; mf < 4; ++mf) {
                int row = wm * 64 + mf * 16 + l15;
                int off = (row * 128 + (ks * 32 + l4 * 8) * 2) ^ ((row & 7) << 4);
                a[mf] = *(const s16x8*)((const char*)Xs + off);
            }
#pragma unroll
            for (int nf = 0; nf < 2; ++nf) {
                int row = wn * 32 + nf * 16 + l15;
                int off = (row * 128 + (ks * 32 + l4 * 8) * 2) ^ ((row & 7) << 4);
                b[nf] = *(const s16x8*)((const char*)Ws + off);
            }
#pragma unroll
            for (int mf = 0; mf < 4; ++mf)
#pragma unroll
                for (int nf = 0; nf < 2; ++nf)
                    acc[mf][nf] = __builtin_amdgcn_mfma_f32_16x16x32_bf16(
                        a[mf], b[nf], acc[mf][nf], 0, 0, 0);
        }
    }

#pragma unroll
    for (int mf = 0; mf < 4; ++mf) {
#pragma unroll
        for (int nf = 0; nf < 2; ++nf) {
            int col   = bn + wn * 32 + nf * 16 + l15;
            int rbase = bm + wm * 64 + mf * 16 + l4 * 4;
            float bv = BIAS ? bias[col] : 0.f;
#pragma unroll
            for (int r = 0; r < 4; ++r) {
                float v = acc[mf][nf][r] + bv;
                if (ACT == 2) v = 0.5f * v * (1.f + erff(v * 0.70710678118654752f));
                size_t o = (size_t)(rbase + r) * N + col;
                if (RES) v += res[o];
                Y[o] = v;
            }
        }
    }
}

// ---------------------------------------------------------------- fp32 GEMM (xproj N=40, dtproj K=8)
template<int ACT, bool BIAS>
__global__ __launch_bounds__(256) void gemm_kernel(
    const float* __restrict__ X, int lda,
    const float* __restrict__ W,
    const float* __restrict__ bias,
    float* __restrict__ Y, int N, int K)
{
    __shared__ __align__(16) float As[16][68];
    __shared__ __align__(16) float Ws[16][68];
    int bm = blockIdx.x * 64;
    int bn = blockIdx.y * 64;
    int tid = threadIdx.x;
    int tm = (tid >> 4) << 2;
    int tn = (tid & 15) << 2;
    float acc[4][4] = {};

    for (int k0 = 0; k0 < K; k0 += 16) {
#pragma unroll
        for (int i = 0; i < 4; ++i) {
            int idx = tid + i * 256;
            int m  = idx >> 4;
            int kk = idx & 15;
            int gk = k0 + kk;
            As[kk][m] = (gk < K) ? X[(size_t)(bm + m) * lda + gk] : 0.f;
            int gn = bn + m;
            Ws[kk][m] = (gk < K && gn < N) ? W[(size_t)gn * K + gk] : 0.f;
        }
        __syncthreads();
#pragma unroll
        for (int kk = 0; kk < 16; ++kk) {
            float4 av = *reinterpret_cast<const float4*>(&As[kk][tm]);
            float4 bv = *reinterpret_cast<const float4*>(&Ws[kk][tn]);
            float a[4] = {av.x, av.y, av.z, av.w};
            float b[4] = {bv.x, bv.y, bv.z, bv.w};
#pragma unroll
            for (int i2 = 0; i2 < 4; ++i2)
#pragma unroll
                for (int j2 = 0; j2 < 4; ++j2)
                    acc[i2][j2] = fmaf(a[i2], b[j2], acc[i2][j2]);
        }
        __syncthreads();
    }
#pragma unroll
    for (int i2 = 0; i2 < 4; ++i2) {
        int gm = bm + tm + i2;
#pragma unroll
        for (int j2 = 0; j2 < 4; ++j2) {
            int gn = bn + tn + j2;
            if (gn < N) {
                float v = acc[i2][j2];
                if (BIAS) v += bias[gn];
                if (ACT == 1) v = (v > 0.f) ? v + log1pf(expf(-v)) : log1pf(expf(v));
                Y[(size_t)gm * N + gn] = v;
            }
        }
    }
}

// ---------------------------------------------------------------- layernorm (8192 rows x 128)
__global__ __launch_bounds__(256) void ln_kernel(
    const float* __restrict__ X, const float* __restrict__ g,
    const float* __restrict__ bb, float* __restrict__ Y)
{
    int row  = blockIdx.x * 4 + (threadIdx.x >> 6);
    int lane = threadIdx.x & 63;
    const float* xr = X + (size_t)row * 128;
    float v0 = xr[lane], v1 = xr[lane + 64];
    float s = v0 + v1;
#pragma unroll
    for (int off = 32; off > 0; off >>= 1) s += __shfl_xor(s, off, 64);
    float mean = s * 0.0078125f;
    float d0 = v0 - mean, d1 = v1 - mean;
    float q = d0 * d0 + d1 * d1;
#pragma unroll
    for (int off = 32; off > 0; off >>= 1) q += __shfl_xor(q, off, 64);
    float rstd = rsqrtf(q * 0.0078125f + 1e-5f);
    float* yr = Y + (size_t)row * 128;
    yr[lane]      = d0 * rstd * g[lane]      + bb[lane];
    yr[lane + 64] = d1 * rstd * g[lane + 64] + bb[lane + 64];
}

// ---------------------------------------------------------------- conv1d (depthwise causal k=4) + silu, float4
__global__ __launch_bounds__(256) void conv_silu_kernel(
    const float* __restrict__ xz, const float* __restrict__ cw,
    const float* __restrict__ cb, float* __restrict__ out)
{
    int i   = blockIdx.x * 256 + threadIdx.x;   // BLC * 64
    int dq  = (i & 63) << 2;
    int row = i >> 6;
    int l   = row & (LSEQ - 1);
    float4 a = *(const float4*)&cb[dq];
    float w[4][4];
#pragma unroll
    for (int e = 0; e < 4; ++e) {
        float4 we = *(const float4*)&cw[(dq + e) * 4];
        w[e][0] = we.x; w[e][1] = we.y; w[e][2] = we.z; w[e][3] = we.w;
    }
#pragma unroll
    for (int j = 0; j < 4; ++j) {
        if (l >= 3 - j) {
            const float4 v = *(const float4*)&xz[(size_t)(row - 3 + j) * 512 + dq];
            a.x = fmaf(v.x, w[0][j], a.x);
            a.y = fmaf(v.y, w[1][j], a.y);
            a.z = fmaf(v.z, w[2][j], a.z);
            a.w = fmaf(v.w, w[3][j], a.w);
        }
    }
    float4 o;
    o.x = a.x / (1.f + __expf(-a.x));
    o.y = a.y / (1.f + __expf(-a.y));
    o.z = a.z / (1.f + __expf(-a.z));
    o.w = a.w / (1.f + __expf(-a.w));
    *(float4*)&out[(size_t)row * 256 + dq] = o;
}

// ---------------------------------------------------------------- chunked selective scan
// wave = 16 n-lanes x 4 consecutive d. grid (16 d-blocks, NC, B).
__global__ __launch_bounds__(256) void scan_phase1(
    const float* __restrict__ dtb, const float* __restrict__ ucv,
    const float* __restrict__ dbl, const float* __restrict__ A_log,
    float* __restrict__ hend, float* __restrict__ aprod)
{
    int n  = threadIdx.x & 15;
    int dl = threadIdx.x >> 4;
    int d  = blockIdx.x * 16 + dl;
    int c  = blockIdx.y;
    int b  = blockIdx.z;
    float An = -__expf(A_log[d * 16 + n]);
    float h = 0.f, ap = 1.f;
    int row0 = b * LSEQ + c * CHK;
    const float* dtp = dtb + (size_t)row0 * 256 + d;
    const float* ucp = ucv + (size_t)row0 * 256 + d;
    const float* dbp = dbl + (size_t)row0 * 40 + 8 + n;
#pragma unroll 4
    for (int t = 0; t < CHK; ++t) {
        float dtv = dtp[t * 256];
        float uv  = ucp[t * 256];
        float bm  = dbp[t * 40];
        float a = __expf(dtv * An);
        h = fmaf(a, h, dtv * uv * bm);
        ap *= a;
    }
    int ch = (b * 256 + d) * 16 + n;
    hend [c * NCH + ch] = h;
    aprod[c * NCH + ch] = ap;
}

// Serial prefix over chunks; h0 written in place of aprod. Coalesced [c][ch] layout.
__global__ __launch_bounds__(256) void scan_phase2(
    const float* __restrict__ hend, float* __restrict__ apr_h0)
{
    int ch = blockIdx.x * 256 + threadIdx.x;   // NCH = 8192 -> 32 blocks
    float h = 0.f;
#pragma unroll
    for (int c = 0; c < NC; ++c) {
        float ap = apr_h0[c * NCH + ch];
        float he = hend[c * NCH + ch];
        apr_h0[c * NCH + ch] = h;
        h = fmaf(ap, h, he);
    }
}

__global__ __launch_bounds__(256) void scan_phase3(
    const float* __restrict__ dtb, const float* __restrict__ ucv,
    const float* __restrict__ dbl, const float* __restrict__ xz,
    const float* __restrict__ A_log, const float* __restrict__ Dp,
    const float* __restrict__ h0, float* __restrict__ y)
{
    int n  = threadIdx.x & 15;
    int dl = threadIdx.x >> 4;
    int d  = blockIdx.x * 16 + dl;
    int c  = blockIdx.y;
    int b  = blockIdx.z;
    float An = -__expf(A_log[d * 16 + n]);
    float Dd = Dp[d];
    int ch = (b * 256 + d) * 16 + n;
    float h = h0[c * NCH + ch];
    int row0 = b * LSEQ + c * CHK;
    const float* dtp = dtb + (size_t)row0 * 256 + d;
    const float* ucp = ucv + (size_t)row0 * 256 + d;
    const float* dbp = dbl + (size_t)row0 * 40;
    const float* xzp = xz  + (size_t)row0 * 512 + 256 + d;
    float* yp = y + (size_t)row0 * 256 + d;
#pragma unroll 2
    for (int t = 0; t < CHK; ++t) {
        float dtv = dtp[t * 256];
        float uv  = ucp[t * 256];
        float bm  = dbp[t * 40 + 8 + n];
        float cm  = dbp[t * 40 + 24 + n];
        float a = __expf(dtv * An);
        h = fmaf(a, h, dtv * uv * bm);
        float p = h * cm;
        p += __shfl_xor(p, 8, 16);
        p += __shfl_xor(p, 4, 16);
        p += __shfl_xor(p, 2, 16);
        p += __shfl_xor(p, 1, 16);
        if (n == 0) {
            float zv = xzp[t * 512];
            float sil = zv / (1.f + __expf(-zv));
            yp[t * 256] = fmaf(uv, Dd, p) * sil;
        }
    }
}

// ---------------------------------------------------------------- launch
extern "C" void kernel_launch(void* const* d_in, const int* in_sizes, int n_in,
                              void* d_out, int out_size, void* d_ws, size_t ws_size,
                              hipStream_t stream)
{
    const float* x        = (const float*)d_in[0];
    const float* embed_w  = (const float*)d_in[1];
    const float* embed_b  = (const float*)d_in[2];
    const float* outc_w   = (const float*)d_in[3];
    const float* outc_b   = (const float*)d_in[4];
    const float* ln_g     = (const float*)d_in[5];
    const float* ln_b     = (const float*)d_in[6];
    const float* in_w     = (const float*)d_in[7];
    const float* conv_w   = (const float*)d_in[8];
    const float* conv_b   = (const float*)d_in[9];
    const float* xproj_w  = (const float*)d_in[10];
    const float* dtproj_w = (const float*)d_in[11];
    const float* dtproj_b = (const float*)d_in[12];
    const float* A_log    = (const float*)d_in[13];
    const float* ssm_D    = (const float*)d_in[14];
    const float* mout_w   = (const float*)d_in[15];
    const float* ffn_w1   = (const float*)d_in[16];
    const float* ffn_b1   = (const float*)d_in[17];
    const float* ffn_w2   = (const float*)d_in[18];
    const float* ffn_b2   = (const float*)d_in[19];

    float* ws   = (float*)d_ws;
    float* t    = ws;                   // (BLC,128)   1,048,576
    float* tmp2 = ws + 1048576;         // (BLC,256)   LN out (first half) / scan out
    float* xzb  = ws + 3145728;         // (BLC,512)   also FFN mid
    float* ucv  = ws + 7340032;         // (BLC,256)
    float* dtb  = ws + 9437184;         // (BLC,256)
    float* dbl  = ws + 11534336;        // (BLC,40)      327,680
    float* hend = ws + 11862016;        // [NC][NCH]     262,144
    float* apr  = ws + 12124160;        // [NC][NCH]     262,144 (becomes h0 in phase2)
    float* out  = (float*)d_out;        // total 12,386,304 floats ≈ 49.5 MB

    dim3 tb(32, 8);
    transpose_kernel<false><<<dim3(128, 4, 2), tb, 0, stream>>>(x, tmp2, nullptr, 128, 4096);
    mgemm<0, true, false><<<dim3(64, 2), 256, 0, stream>>>(tmp2, embed_w, embed_b, nullptr, t, 128, 128);

    for (int i = 0; i < 2; ++i) {
        ln_kernel<<<2048, 256, 0, stream>>>(t, ln_g + i * 128, ln_b + i * 128, tmp2);
        mgemm<0, false, false><<<dim3(64, 8), 256, 0, stream>>>(tmp2, in_w + i * 65536, nullptr, nullptr, xzb, 512, 128);
        conv_silu_kernel<<<2048, 256, 0, stream>>>(xzb, conv_w + i * 1024, conv_b + i * 256, ucv);
        gemm_kernel<0, false><<<dim3(128, 1), 256, 0, stream>>>(ucv, 256, xproj_w + i * 10240, nullptr, dbl, 40, 256);
        gemm_kernel<1, true><<<dim3(128, 4), 256, 0, stream>>>(dbl, 40, dtproj_w + i * 2048, dtproj_b + i * 256, dtb, 256, 8);
        scan_phase1<<<dim3(16, NC, 2), 256, 0, stream>>>(dtb, ucv, dbl, A_log + i * 4096, hend, apr);
        scan_phase2<<<32, 256, 0, stream>>>(hend, apr);
        scan_phase3<<<dim3(16, NC, 2), 256, 0, stream>>>(dtb, ucv, dbl, xzb, A_log + i * 4096, ssm_D + i * 256, apr, tmp2);
        mgemm<0, false, true><<<dim3(64, 2), 256, 0, stream>>>(tmp2, mout_w + i * 32768, nullptr, t, t, 128, 256);
        ln_kernel<<<2048, 256, 0, stream>>>(t, ln_g + i * 128, ln_b + i * 128, tmp2);
        mgemm<2, true, false><<<dim3(64, 8), 256, 0, stream>>>(tmp2, ffn_w1 + i * 65536, ffn_b1 + i * 512, nullptr, xzb, 512, 128);
        mgemm<0, true, true><<<dim3(64, 2), 256, 0, stream>>>(xzb, ffn_w2 + i * 65536, ffn_b2 + i * 128, t, t, 128, 512);
    }

    mgemm<0, true, false><<<dim3(64, 2), 256, 0, stream>>>(t, outc_w, outc_b, nullptr, tmp2, 128, 128);
    transpose_kernel<true><<<dim3(4, 128, 2), tb, 0, stream>>>(tmp2, out, x, 4096, 128);
}

// Round 5
// 540.851 us; speedup vs baseline: 1.5804x; 1.0546x over previous
//
#include <hip/hip_runtime.h>
#include <hip/hip_bf16.h>

// MambaFeatureEnhancer — B=2, C=128, L=4096, d_inner=256, N=16, R=8, 2 layers. All I/O fp32.
// Big GEMMs: bf16 MFMA (fp32 accum). dt path (xproj/dtproj) + scan stay fp32.
// Scan operands staged channel-major (dtT/dtuT/BCt) for float4 ILP. ws = 52.7 MB.

#define LSEQ 4096
#define BLC  8192      // B * L
#define NC   64        // scan chunks
#define CHK  64        // chunk length
#define NCH  8192      // B * d_inner * N state channels

typedef __attribute__((ext_vector_type(4))) float f32x4;
typedef __attribute__((ext_vector_type(8))) short s16x8;

__device__ __forceinline__ unsigned short f2bu(float f) {   // fp32 -> bf16 bits, RNE
    unsigned u = __float_as_uint(f);
    return (unsigned short)((u + 0x7fffu + ((u >> 16) & 1u)) >> 16);
}

// ---------------------------------------------------------------- transpose (I/O reshape)
template<bool ADD>
__global__ __launch_bounds__(256) void transpose_kernel(
    const float* __restrict__ in_, float* __restrict__ out_,
    const float* __restrict__ add, int R, int Cc)
{
    __shared__ float tile[32][33];
    size_t boff = (size_t)blockIdx.z * R * Cc;
    int r0 = blockIdx.y * 32, c0 = blockIdx.x * 32;
    int tx = threadIdx.x, ty = threadIdx.y;   // block (32,8)
#pragma unroll
    for (int j = 0; j < 4; ++j)
        tile[ty + j * 8][tx] = in_[boff + (size_t)(r0 + ty + j * 8) * Cc + (c0 + tx)];
    __syncthreads();
#pragma unroll
    for (int j = 0; j < 4; ++j) {
        size_t idx = boff + (size_t)(c0 + ty + j * 8) * R + (r0 + tx);
        float v = tile[tx][ty + j * 8];
        if (ADD) v += add[idx];
        out_[idx] = v;
    }
}

// ---------------------------------------------------------------- scan-prep transpose
// in (R rows, stride si, cols col_off..col_off+Cc) -> out [Cc][R]; MUL: multiply by in2 (same indexing)
template<bool MUL>
__global__ __launch_bounds__(256) void transposeN(
    const float* __restrict__ in_, const float* __restrict__ in2,
    float* __restrict__ out_, int si, int col_off, int R)
{
    __shared__ float tile[32][33];
    int r0 = blockIdx.y * 32, c0 = blockIdx.x * 32;
    int tx = threadIdx.x, ty = threadIdx.y;   // block (32,8)
#pragma unroll
    for (int j = 0; j < 4; ++j) {
        int r = r0 + ty + j * 8;
        size_t idx = (size_t)r * si + col_off + c0 + tx;
        float v = in_[idx];
        if (MUL) v *= in2[idx];
        tile[ty + j * 8][tx] = v;
    }
    __syncthreads();
#pragma unroll
    for (int j = 0; j < 4; ++j)
        out_[(size_t)(c0 + ty + j * 8) * R + r0 + tx] = tile[tx][ty + j * 8];
}

// ---------------------------------------------------------------- bf16 MFMA GEMM
// Y[m,n] = act( sum_k X[m,k]*W[n,k] + bias[n] ) (+ res[m,n])
// X fp32 (M x K), W fp32 (N x K), Y fp32. M=8192. BN=64. 4 waves (2x2).
// SPLIT: N=512, cols<256 -> Y (stride 256), cols>=256 -> Y2 (stride 256).
template<int BM, int ACT, bool BIAS, bool RES, bool SPLIT>
__global__ __launch_bounds__(256) void mgemm(
    const float* __restrict__ X, const float* __restrict__ W,
    const float* __restrict__ bias, const float* __restrict__ res,
    float* __restrict__ Y, float* __restrict__ Y2, int N, int K)
{
    constexpr int MF = BM / 32;            // m-fragments per wave
    __shared__ __align__(16) unsigned short Xs[BM * 64];
    __shared__ __align__(16) unsigned short Ws[64 * 64];
    int tid  = threadIdx.x;
    int lane = tid & 63;
    int wave = tid >> 6;
    int wm = wave >> 1, wn = wave & 1;
    int l15 = lane & 15, l4 = lane >> 4;
    int bm = blockIdx.x * BM, bn = blockIdx.y * 64;
    f32x4 acc[MF][2] = {};

    int q  = tid & 15;     // col-quad (4 floats)
    int r0 = tid >> 4;     // 0..15

    for (int k0 = 0; k0 < K; k0 += 64) {
        __syncthreads();
#pragma unroll
        for (int p = 0; p < BM / 16; ++p) {                 // stage X: BM x 64
            int row = r0 + p * 16;
            float4 v = *(const float4*)&X[(size_t)(bm + row) * K + k0 + q * 4];
            unsigned lo = f2bu(v.x) | ((unsigned)f2bu(v.y) << 16);
            unsigned hi = f2bu(v.z) | ((unsigned)f2bu(v.w) << 16);
            int off = (row * 128 + q * 8) ^ ((row & 7) << 4);
            *(uint2*)((char*)Xs + off) = make_uint2(lo, hi);
        }
#pragma unroll
        for (int p = 0; p < 4; ++p) {                       // stage W: 64x64
            int row = r0 + p * 16;
            float4 v = *(const float4*)&W[(size_t)(bn + row) * K + k0 + q * 4];
            unsigned lo = f2bu(v.x) | ((unsigned)f2bu(v.y) << 16);
            unsigned hi = f2bu(v.z) | ((unsigned)f2bu(v.w) << 16);
            int off = (row * 128 + q * 8) ^ ((row & 7) << 4);
            *(uint2*)((char*)Ws + off) = make_uint2(lo, hi);
        }
        __syncthreads();
#pragma unroll
        for (int ks = 0; ks < 2; ++ks) {
            s16x8 a[MF], b[2];
#pragma unroll
            for (int mf = 0; mf < MF; ++mf) {
                int row = wm * (BM / 2) + mf * 16 + l15;
                int off = (row * 128 + (ks * 32 + l4 * 8) * 2) ^ ((row & 7) << 4);
                a[mf] = *(const s16x8*)((const char*)Xs + off);
            }
#pragma unroll
            for (int nf = 0; nf < 2; ++nf) {
                int row = wn * 32 + nf * 16 + l15;
                int off = (row * 128 + (ks * 32 + l4 * 8) * 2) ^ ((row & 7) << 4);
                b[nf] = *(const s16x8*)((const char*)Ws + off);
            }
#pragma unroll
            for (int mf = 0; mf < MF; ++mf)
#pragma unroll
                for (int nf = 0; nf < 2; ++nf)
                    acc[mf][nf] = __builtin_amdgcn_mfma_f32_16x16x32_bf16(
                        a[mf], b[nf], acc[mf][nf], 0, 0, 0);
        }
    }

#pragma unroll
    for (int mf = 0; mf < MF; ++mf) {
#pragma unroll
        for (int nf = 0; nf < 2; ++nf) {
            int col   = bn + wn * 32 + nf * 16 + l15;
            int rbase = bm + wm * (BM / 2) + mf * 16 + l4 * 4;
            float bv = BIAS ? bias[col] : 0.f;
#pragma unroll
            for (int r = 0; r < 4; ++r) {
                float v = acc[mf][nf][r] + bv;
                if (ACT == 2) v = 0.5f * v * (1.f + erff(v * 0.70710678118654752f));
                if (SPLIT) {
                    if (col < 256) Y [(size_t)(rbase + r) * 256 + col]       = v;
                    else           Y2[(size_t)(rbase + r) * 256 + col - 256] = v;
                } else {
                    size_t o = (size_t)(rbase + r) * N + col;
                    if (RES) v += res[o];
                    Y[o] = v;
                }
            }
        }
    }
}

// ---------------------------------------------------------------- fp32 GEMM (xproj N=40, dtproj K=8)
template<int ACT, bool BIAS>
__global__ __launch_bounds__(256) void gemm_kernel(
    const float* __restrict__ X, int lda,
    const float* __restrict__ W,
    const float* __restrict__ bias,
    float* __restrict__ Y, int N, int K)
{
    __shared__ __align__(16) float As[16][68];
    __shared__ __align__(16) float Ws[16][68];
    int bm = blockIdx.x * 64;
    int bn = blockIdx.y * 64;
    int tid = threadIdx.x;
    int tm = (tid >> 4) << 2;
    int tn = (tid & 15) << 2;
    float acc[4][4] = {};

    for (int k0 = 0; k0 < K; k0 += 16) {
#pragma unroll
        for (int i = 0; i < 4; ++i) {
            int idx = tid + i * 256;
            int m  = idx >> 4;
            int kk = idx & 15;
            int gk = k0 + kk;
            As[kk][m] = (gk < K) ? X[(size_t)(bm + m) * lda + gk] : 0.f;
            int gn = bn + m;
            Ws[kk][m] = (gk < K && gn < N) ? W[(size_t)gn * K + gk] : 0.f;
        }
        __syncthreads();
#pragma unroll
        for (int kk = 0; kk < 16; ++kk) {
            float4 av = *reinterpret_cast<const float4*>(&As[kk][tm]);
            float4 bv = *reinterpret_cast<const float4*>(&Ws[kk][tn]);
            float a[4] = {av.x, av.y, av.z, av.w};
            float b[4] = {bv.x, bv.y, bv.z, bv.w};
#pragma unroll
            for (int i2 = 0; i2 < 4; ++i2)
#pragma unroll
                for (int j2 = 0; j2 < 4; ++j2)
                    acc[i2][j2] = fmaf(a[i2], b[j2], acc[i2][j2]);
        }
        __syncthreads();
    }
#pragma unroll
    for (int i2 = 0; i2 < 4; ++i2) {
        int gm = bm + tm + i2;
#pragma unroll
        for (int j2 = 0; j2 < 4; ++j2) {
            int gn = bn + tn + j2;
            if (gn < N) {
                float v = acc[i2][j2];
                if (BIAS) v += bias[gn];
                if (ACT == 1) v = (v > 0.f) ? v + log1pf(expf(-v)) : log1pf(expf(v));
                Y[(size_t)gm * N + gn] = v;
            }
        }
    }
}

// ---------------------------------------------------------------- layernorm (8192 rows x 128)
__global__ __launch_bounds__(256) void ln_kernel(
    const float* __restrict__ X, const float* __restrict__ g,
    const float* __restrict__ bb, float* __restrict__ Y)
{
    int row  = blockIdx.x * 4 + (threadIdx.x >> 6);
    int lane = threadIdx.x & 63;
    const float* xr = X + (size_t)row * 128;
    float v0 = xr[lane], v1 = xr[lane + 64];
    float s = v0 + v1;
#pragma unroll
    for (int off = 32; off > 0; off >>= 1) s += __shfl_xor(s, off, 64);
    float mean = s * 0.0078125f;
    float d0 = v0 - mean, d1 = v1 - mean;
    float q = d0 * d0 + d1 * d1;
#pragma unroll
    for (int off = 32; off > 0; off >>= 1) q += __shfl_xor(q, off, 64);
    float rstd = rsqrtf(q * 0.0078125f + 1e-5f);
    float* yr = Y + (size_t)row * 128;
    yr[lane]      = d0 * rstd * g[lane]      + bb[lane];
    yr[lane + 64] = d1 * rstd * g[lane + 64] + bb[lane + 64];
}

// ---------------------------------------------------------------- conv1d (depthwise causal k=4) + silu
// u: (BLC x 256, stride 256) -> ucv (BLC x 256)
__global__ __launch_bounds__(256) void conv_silu_kernel(
    const float* __restrict__ u, const float* __restrict__ cw,
    const float* __restrict__ cb, float* __restrict__ out)
{
    int i   = blockIdx.x * 256 + threadIdx.x;   // BLC * 64
    int dq  = (i & 63) << 2;
    int row = i >> 6;
    int l   = row & (LSEQ - 1);
    float4 a = *(const float4*)&cb[dq];
    float w[4][4];
#pragma unroll
    for (int e = 0; e < 4; ++e) {
        float4 we = *(const float4*)&cw[(dq + e) * 4];
        w[e][0] = we.x; w[e][1] = we.y; w[e][2] = we.z; w[e][3] = we.w;
    }
#pragma unroll
    for (int j = 0; j < 4; ++j) {
        if (l >= 3 - j) {
            const float4 v = *(const float4*)&u[(size_t)(row - 3 + j) * 256 + dq];
            a.x = fmaf(v.x, w[0][j], a.x);
            a.y = fmaf(v.y, w[1][j], a.y);
            a.z = fmaf(v.z, w[2][j], a.z);
            a.w = fmaf(v.w, w[3][j], a.w);
        }
    }
    float4 o;
    o.x = a.x / (1.f + __expf(-a.x));
    o.y = a.y / (1.f + __expf(-a.y));
    o.z = a.z / (1.f + __expf(-a.z));
    o.w = a.w / (1.f + __expf(-a.w));
    *(float4*)&out[(size_t)row * 256 + dq] = o;
}

// ---------------------------------------------------------------- chunked selective scan
// wave = 16 n-lanes x 4 consecutive d. grid (16, NC, B). Channel-major float4 operands.
__global__ __launch_bounds__(256) void scan_phase1(
    const float* __restrict__ dtT, const float* __restrict__ dtuT,
    const float* __restrict__ Bt, const float* __restrict__ A_log,
    float* __restrict__ hend, float* __restrict__ aprod)
{
    int n  = threadIdx.x & 15;
    int dl = threadIdx.x >> 4;
    int d  = blockIdx.x * 16 + dl;
    int c  = blockIdx.y;
    int b  = blockIdx.z;
    float An = -__expf(A_log[d * 16 + n]);
    int base  = d * BLC + b * LSEQ + c * CHK;
    int bbase = n * BLC + b * LSEQ + c * CHK;
    float h = 0.f, ap = 1.f;
#pragma unroll 4
    for (int t4 = 0; t4 < CHK; t4 += 4) {
        float4 dt4 = *(const float4*)&dtT[base + t4];
        float4 du4 = *(const float4*)&dtuT[base + t4];
        float4 B4  = *(const float4*)&Bt[bbase + t4];
        float a;
        a = __expf(dt4.x * An); h = fmaf(a, h, du4.x * B4.x); ap *= a;
        a = __expf(dt4.y * An); h = fmaf(a, h, du4.y * B4.y); ap *= a;
        a = __expf(dt4.z * An); h = fmaf(a, h, du4.z * B4.z); ap *= a;
        a = __expf(dt4.w * An); h = fmaf(a, h, du4.w * B4.w); ap *= a;
    }
    int ch = (b * 256 + d) * 16 + n;
    hend [c * NCH + ch] = h;
    aprod[c * NCH + ch] = ap;
}

// Serial prefix over chunks; h0 written in place of aprod. Coalesced [c][ch] layout.
__global__ __launch_bounds__(256) void scan_phase2(
    const float* __restrict__ hend, float* __restrict__ apr_h0)
{
    int ch = blockIdx.x * 256 + threadIdx.x;   // NCH
    float h = 0.f;
#pragma unroll
    for (int c = 0; c < NC; ++c) {
        float ap = apr_h0[c * NCH + ch];
        float he = hend[c * NCH + ch];
        apr_h0[c * NCH + ch] = h;
        h = fmaf(ap, h, he);
    }
}

// Phase 3: recompute from h0, reduce over n, write raw scan output y[row][d].
__global__ __launch_bounds__(256) void scan_phase3(
    const float* __restrict__ dtT, const float* __restrict__ dtuT,
    const float* __restrict__ Bt, const float* __restrict__ Ct,
    const float* __restrict__ A_log, const float* __restrict__ h0,
    float* __restrict__ y)
{
    int n  = threadIdx.x & 15;
    int dl = threadIdx.x >> 4;
    int d  = blockIdx.x * 16 + dl;
    int c  = blockIdx.y;
    int b  = blockIdx.z;
    float An = -__expf(A_log[d * 16 + n]);
    int base  = d * BLC + b * LSEQ + c * CHK;
    int bbase = n * BLC + b * LSEQ + c * CHK;
    int ch = (b * 256 + d) * 16 + n;
    float h = h0[c * NCH + ch];
    int row0 = b * LSEQ + c * CHK;
#pragma unroll 4
    for (int t4 = 0; t4 < CHK; t4 += 4) {
        float4 dt4 = *(const float4*)&dtT[base + t4];
        float4 du4 = *(const float4*)&dtuT[base + t4];
        float4 B4  = *(const float4*)&Bt[bbase + t4];
        float4 C4  = *(const float4*)&Ct[bbase + t4];
        float av[4] = {dt4.x, dt4.y, dt4.z, dt4.w};
        float uv[4] = {du4.x, du4.y, du4.z, du4.w};
        float bv[4] = {B4.x, B4.y, B4.z, B4.w};
        float cv[4] = {C4.x, C4.y, C4.z, C4.w};
#pragma unroll
        for (int j = 0; j < 4; ++j) {
            float a = __expf(av[j] * An);
            h = fmaf(a, h, uv[j] * bv[j]);
            float p = h * cv[j];
            p += __shfl_xor(p, 8, 16);
            p += __shfl_xor(p, 4, 16);
            p += __shfl_xor(p, 2, 16);
            p += __shfl_xor(p, 1, 16);
            if (n == 0) y[(size_t)(row0 + t4 + j) * 256 + d] = p;
        }
    }
}

// ---------------------------------------------------------------- ymerge: ym = (y + u*D) * silu(z)
__global__ __launch_bounds__(256) void ymerge_kernel(
    const float* __restrict__ y, const float* __restrict__ u,
    const float* __restrict__ z, const float* __restrict__ D,
    float* __restrict__ out)
{
    int i  = (blockIdx.x * 256 + threadIdx.x) * 4;
    int dq = i & 255;
    float4 y4 = *(const float4*)&y[i];
    float4 u4 = *(const float4*)&u[i];
    float4 z4 = *(const float4*)&z[i];
    float4 D4 = *(const float4*)&D[dq];
    float4 o;
    o.x = fmaf(u4.x, D4.x, y4.x) * (z4.x / (1.f + __expf(-z4.x)));
    o.y = fmaf(u4.y, D4.y, y4.y) * (z4.y / (1.f + __expf(-z4.y)));
    o.z = fmaf(u4.z, D4.z, y4.z) * (z4.z / (1.f + __expf(-z4.z)));
    o.w = fmaf(u4.w, D4.w, y4.w) * (z4.w / (1.f + __expf(-z4.w)));
    *(float4*)&out[i] = o;
}

// ---------------------------------------------------------------- launch
extern "C" void kernel_launch(void* const* d_in, const int* in_sizes, int n_in,
                              void* d_out, int out_size, void* d_ws, size_t ws_size,
                              hipStream_t stream)
{
    const float* x        = (const float*)d_in[0];
    const float* embed_w  = (const float*)d_in[1];
    const float* embed_b  = (const float*)d_in[2];
    const float* outc_w   = (const float*)d_in[3];
    const float* outc_b   = (const float*)d_in[4];
    const float* ln_g     = (const float*)d_in[5];
    const float* ln_b     = (const float*)d_in[6];
    const float* in_w     = (const float*)d_in[7];
    const float* conv_w   = (const float*)d_in[8];
    const float* conv_b   = (const float*)d_in[9];
    const float* xproj_w  = (const float*)d_in[10];
    const float* dtproj_w = (const float*)d_in[11];
    const float* dtproj_b = (const float*)d_in[12];
    const float* A_log    = (const float*)d_in[13];
    const float* ssm_D    = (const float*)d_in[14];
    const float* mout_w   = (const float*)d_in[15];
    const float* ffn_w1   = (const float*)d_in[16];
    const float* ffn_b1   = (const float*)d_in[17];
    const float* ffn_w2   = (const float*)d_in[18];
    const float* ffn_b2   = (const float*)d_in[19];

    float* ws   = (float*)d_ws;
    float* t    = ws;                   // (BLC,128)  1M
    float* tmp2 = ws + 1048576;         // 2M: LN-out / dtuT / ym
    float* ub   = ws + 3145728;         // 2M: in_proj u / dtT       (ffn-mid spans ub..zb)
    float* zb   = ws + 5242880;         // 2M: in_proj z
    float* ucv  = ws + 7340032;         // 2M: conv+silu out
    float* dtb  = ws + 9437184;         // 2M: dt / y_scan
    float* dbl  = ws + 11534336;        // (BLC,40)   327,680
    float* bct  = ws + 11862016;        // [32][BLC]  262,144  (B rows 0-15, C rows 16-31)
    float* hend = ws + 12124160;        // [NC][NCH]  524,288
    float* apr  = ws + 12648448;        // [NC][NCH]  524,288  -> h0
    float* out  = (float*)d_out;        // total 13,172,736 floats = 52.7 MB

    float* dtT  = ub;
    float* dtuT = tmp2;
    float* Bt   = bct;
    float* Ct   = bct + 16 * BLC;
    float* ffnmid = ub;                 // spans ub+zb (BLC x 512)

    dim3 tb(32, 8);
    transpose_kernel<false><<<dim3(128, 4, 2), tb, 0, stream>>>(x, tmp2, nullptr, 128, 4096);
    mgemm<64, 0, true, false, false><<<dim3(128, 2), 256, 0, stream>>>(tmp2, embed_w, embed_b, nullptr, t, nullptr, 128, 128);

    for (int i = 0; i < 2; ++i) {
        ln_kernel<<<2048, 256, 0, stream>>>(t, ln_g + i * 128, ln_b + i * 128, tmp2);
        mgemm<128, 0, false, false, true><<<dim3(64, 8), 256, 0, stream>>>(tmp2, in_w + i * 65536, nullptr, nullptr, ub, zb, 512, 128);
        conv_silu_kernel<<<2048, 256, 0, stream>>>(ub, conv_w + i * 1024, conv_b + i * 256, ucv);
        gemm_kernel<0, false><<<dim3(128, 1), 256, 0, stream>>>(ucv, 256, xproj_w + i * 10240, nullptr, dbl, 40, 256);
        gemm_kernel<1, true><<<dim3(128, 4), 256, 0, stream>>>(dbl, 40, dtproj_w + i * 2048, dtproj_b + i * 256, dtb, 256, 8);
        // scan prep: dtT, dtuT, BCt (channel-major)
        transposeN<false><<<dim3(8, 256), tb, 0, stream>>>(dtb, nullptr, dtT, 256, 0, BLC);
        transposeN<true ><<<dim3(8, 256), tb, 0, stream>>>(dtb, ucv, dtuT, 256, 0, BLC);
        transposeN<false><<<dim3(1, 256), tb, 0, stream>>>(dbl, nullptr, bct, 40, 8, BLC);
        scan_phase1<<<dim3(16, NC, 2), 256, 0, stream>>>(dtT, dtuT, Bt, A_log + i * 4096, hend, apr);
        scan_phase2<<<32, 256, 0, stream>>>(hend, apr);
        scan_phase3<<<dim3(16, NC, 2), 256, 0, stream>>>(dtT, dtuT, Bt, Ct, A_log + i * 4096, apr, dtb);
        ymerge_kernel<<<2048, 256, 0, stream>>>(dtb, ucv, zb, ssm_D + i * 256, tmp2);
        mgemm<64, 0, false, true, false><<<dim3(128, 2), 256, 0, stream>>>(tmp2, mout_w + i * 32768, nullptr, t, t, nullptr, 128, 256);
        ln_kernel<<<2048, 256, 0, stream>>>(t, ln_g + i * 128, ln_b + i * 128, tmp2);
        mgemm<128, 2, true, false, false><<<dim3(64, 8), 256, 0, stream>>>(tmp2, ffn_w1 + i * 65536, ffn_b1 + i * 512, nullptr, ffnmid, nullptr, 512, 128);
        mgemm<64, 0, true, true, false><<<dim3(128, 2), 256, 0, stream>>>(ffnmid, ffn_w2 + i * 65536, ffn_b2 + i * 128, t, t, nullptr, 128, 512);
    }

    mgemm<64, 0, true, false, false><<<dim3(128, 2), 256, 0, stream>>>(t, outc_w, outc_b, nullptr, tmp2, nullptr, 128, 128);
    transpose_kernel<true><<<dim3(4, 128, 2), tb, 0, stream>>>(tmp2, out, x, 4096, 128);
}

// Round 7
// 451.071 us; speedup vs baseline: 1.8950x; 1.1990x over previous
//
#include <hip/hip_runtime.h>
#include <hip/hip_bf16.h>

// MambaFeatureEnhancer — B=2, C=128, H=W=64 -> L=4096, d_inner=256, N=16, R=8, 2 layers. All I/O fp32.
// Big GEMMs: bf16 MFMA (fp32 accum). dt path (xproj/dtproj) + scan stay fp32.
// Scan: 4 n-states per lane (ILP-4 h-chain, 2-shuffle reduction), B/C broadcast from dbl.

#define LSEQ 4096
#define BLC  8192      // B * L
#define NC   64        // scan chunks
#define CHK  64        // chunk length
#define NCH  8192      // B * d_inner * N state channels

typedef __attribute__((ext_vector_type(4))) float f32x4;
typedef __attribute__((ext_vector_type(8))) short s16x8;

__device__ __forceinline__ unsigned short f2bu(float f) {   // fp32 -> bf16 bits, RNE
    unsigned u = __float_as_uint(f);
    return (unsigned short)((u + 0x7fffu + ((u >> 16) & 1u)) >> 16);
}

// ---------------------------------------------------------------- transpose (I/O reshape)
template<bool ADD>
__global__ __launch_bounds__(256) void transpose_kernel(
    const float* __restrict__ in_, float* __restrict__ out_,
    const float* __restrict__ add, int R, int Cc)
{
    __shared__ float tile[32][33];
    size_t boff = (size_t)blockIdx.z * R * Cc;
    int r0 = blockIdx.y * 32, c0 = blockIdx.x * 32;
    int tx = threadIdx.x, ty = threadIdx.y;   // block (32,8)
#pragma unroll
    for (int j = 0; j < 4; ++j)
        tile[ty + j * 8][tx] = in_[boff + (size_t)(r0 + ty + j * 8) * Cc + (c0 + tx)];
    __syncthreads();
#pragma unroll
    for (int j = 0; j < 4; ++j) {
        size_t idx = boff + (size_t)(c0 + ty + j * 8) * R + (r0 + tx);
        float v = tile[tx][ty + j * 8];
        if (ADD) v += add[idx];
        out_[idx] = v;
    }
}

// ---------------------------------------------------------------- dt/dtu transpose (scan prep)
// dt (BLC,256) + u (BLC,256) -> dtT [256][BLC], dtuT [256][BLC] (dtu = dt*u)
__global__ __launch_bounds__(256) void transposeDT(
    const float* __restrict__ dt, const float* __restrict__ u,
    float* __restrict__ dtT, float* __restrict__ dtuT)
{
    __shared__ float t1[32][33];
    __shared__ float t2[32][33];
    int r0 = blockIdx.y * 32, c0 = blockIdx.x * 32;
    int tx = threadIdx.x, ty = threadIdx.y;   // block (32,8)
#pragma unroll
    for (int j = 0; j < 4; ++j) {
        size_t idx = (size_t)(r0 + ty + j * 8) * 256 + (c0 + tx);
        float a = dt[idx], b = u[idx];
        t1[ty + j * 8][tx] = a;
        t2[ty + j * 8][tx] = a * b;
    }
    __syncthreads();
#pragma unroll
    for (int j = 0; j < 4; ++j) {
        size_t o = (size_t)(c0 + ty + j * 8) * BLC + (r0 + tx);
        dtT [o] = t1[tx][ty + j * 8];
        dtuT[o] = t2[tx][ty + j * 8];
    }
}

// ---------------------------------------------------------------- bf16 MFMA GEMM
// Y[m,n] = act( sum_k X[m,k]*W[n,k] + bias[n] ) (+ res[m,n])
// X fp32 (M x K), W fp32 (N x K), Y fp32. M=8192. BN=64. 4 waves (2x2).
// SPLIT: N=512, cols<256 -> Y (stride 256), cols>=256 -> Y2 (stride 256).
// EPI (K=256): X[m,k] := (X[m,k] + pu[m,k]*pD[k]) * silu(pz[m,k])  during staging.
template<int BM, int ACT, bool BIAS, bool RES, bool SPLIT, bool EPI>
__global__ __launch_bounds__(256) void mgemm(
    const float* __restrict__ X, const float* __restrict__ W,
    const float* __restrict__ bias, const float* __restrict__ res,
    const float* __restrict__ pu, const float* __restrict__ pz,
    const float* __restrict__ pD,
    float* __restrict__ Y, float* __restrict__ Y2, int N, int K)
{
    constexpr int MF = BM / 32;            // m-fragments per wave
    __shared__ __align__(16) unsigned short Xs[BM * 64];
    __shared__ __align__(16) unsigned short Ws[64 * 64];
    int tid  = threadIdx.x;
    int lane = tid & 63;
    int wave = tid >> 6;
    int wm = wave >> 1, wn = wave & 1;
    int l15 = lane & 15, l4 = lane >> 4;
    int bm = blockIdx.x * BM, bn = blockIdx.y * 64;
    f32x4 acc[MF][2] = {};

    int q  = tid & 15;     // col-quad (4 floats)
    int r0 = tid >> 4;     // 0..15

    for (int k0 = 0; k0 < K; k0 += 64) {
        __syncthreads();
#pragma unroll
        for (int p = 0; p < BM / 16; ++p) {                 // stage X: BM x 64
            int row = r0 + p * 16;
            size_t gi = (size_t)(bm + row) * K + k0 + q * 4;
            float4 v = *(const float4*)&X[gi];
            if (EPI) {
                float4 u4 = *(const float4*)&pu[gi];
                float4 z4 = *(const float4*)&pz[gi];
                float4 D4 = *(const float4*)&pD[k0 + q * 4];
                v.x = fmaf(u4.x, D4.x, v.x) * (z4.x / (1.f + __expf(-z4.x)));
                v.y = fmaf(u4.y, D4.y, v.y) * (z4.y / (1.f + __expf(-z4.y)));
                v.z = fmaf(u4.z, D4.z, v.z) * (z4.z / (1.f + __expf(-z4.z)));
                v.w = fmaf(u4.w, D4.w, v.w) * (z4.w / (1.f + __expf(-z4.w)));
            }
            unsigned lo = f2bu(v.x) | ((unsigned)f2bu(v.y) << 16);
            unsigned hi = f2bu(v.z) | ((unsigned)f2bu(v.w) << 16);
            int off = (row * 128 + q * 8) ^ ((row & 7) << 4);
            *(uint2*)((char*)Xs + off) = make_uint2(lo, hi);
        }
#pragma unroll
        for (int p = 0; p < 4; ++p) {                       // stage W: 64x64
            int row = r0 + p * 16;
            float4 v = *(const float4*)&W[(size_t)(bn + row) * K + k0 + q * 4];
            unsigned lo = f2bu(v.x) | ((unsigned)f2bu(v.y) << 16);
            unsigned hi = f2bu(v.z) | ((unsigned)f2bu(v.w) << 16);
            int off = (row * 128 + q * 8) ^ ((row & 7) << 4);
            *(uint2*)((char*)Ws + off) = make_uint2(lo, hi);
        }
        __syncthreads();
#pragma unroll
        for (int ks = 0; ks < 2; ++ks) {
            s16x8 a[MF], b[2];
#pragma unroll
            for (int mf = 0; mf < MF; ++mf) {
                int row = wm * (BM / 2) + mf * 16 + l15;
                int off = (row * 128 + (ks * 32 + l4 * 8) * 2) ^ ((row & 7) << 4);
                a[mf] = *(const s16x8*)((const char*)Xs + off);
            }
#pragma unroll
            for (int nf = 0; nf < 2; ++nf) {
                int row = wn * 32 + nf * 16 + l15;
                int off = (row * 128 + (ks * 32 + l4 * 8) * 2) ^ ((row & 7) << 4);
                b[nf] = *(const s16x8*)((const char*)Ws + off);
            }
#pragma unroll
            for (int mf = 0; mf < MF; ++mf)
#pragma unroll
                for (int nf = 0; nf < 2; ++nf)
                    acc[mf][nf] = __builtin_amdgcn_mfma_f32_16x16x32_bf16(
                        a[mf], b[nf], acc[mf][nf], 0, 0, 0);
        }
    }

#pragma unroll
    for (int mf = 0; mf < MF; ++mf) {
#pragma unroll
        for (int nf = 0; nf < 2; ++nf) {
            int col   = bn + wn * 32 + nf * 16 + l15;
            int rbase = bm + wm * (BM / 2) + mf * 16 + l4 * 4;
            float bv = BIAS ? bias[col] : 0.f;
#pragma unroll
            for (int r = 0; r < 4; ++r) {
                float v = acc[mf][nf][r] + bv;
                if (ACT == 2) v = 0.5f * v * (1.f + erff(v * 0.70710678118654752f));
                if (SPLIT) {
                    if (col < 256) Y [(size_t)(rbase + r) * 256 + col]       = v;
                    else           Y2[(size_t)(rbase + r) * 256 + col - 256] = v;
                } else {
                    size_t o = (size_t)(rbase + r) * N + col;
                    if (RES) v += res[o];
                    Y[o] = v;
                }
            }
        }
    }
}

// ---------------------------------------------------------------- fp32 GEMM (xproj N=40, dtproj K=8)
template<int ACT, bool BIAS>
__global__ __launch_bounds__(256) void gemm_kernel(
    const float* __restrict__ X, int lda,
    const float* __restrict__ W,
    const float* __restrict__ bias,
    float* __restrict__ Y, int N, int K)
{
    __shared__ __align__(16) float As[16][68];
    __shared__ __align__(16) float Ws[16][68];
    int bm = blockIdx.x * 64;
    int bn = blockIdx.y * 64;
    int tid = threadIdx.x;
    int tm = (tid >> 4) << 2;
    int tn = (tid & 15) << 2;
    float acc[4][4] = {};

    for (int k0 = 0; k0 < K; k0 += 16) {
#pragma unroll
        for (int i = 0; i < 4; ++i) {
            int idx = tid + i * 256;
            int m  = idx >> 4;
            int kk = idx & 15;
            int gk = k0 + kk;
            As[kk][m] = (gk < K) ? X[(size_t)(bm + m) * lda + gk] : 0.f;
            int gn = bn + m;
            Ws[kk][m] = (gk < K && gn < N) ? W[(size_t)gn * K + gk] : 0.f;
        }
        __syncthreads();
#pragma unroll
        for (int kk = 0; kk < 16; ++kk) {
            float4 av = *reinterpret_cast<const float4*>(&As[kk][tm]);
            float4 bv = *reinterpret_cast<const float4*>(&Ws[kk][tn]);
            float a[4] = {av.x, av.y, av.z, av.w};
            float b[4] = {bv.x, bv.y, bv.z, bv.w};
#pragma unroll
            for (int i2 = 0; i2 < 4; ++i2)
#pragma unroll
                for (int j2 = 0; j2 < 4; ++j2)
                    acc[i2][j2] = fmaf(a[i2], b[j2], acc[i2][j2]);
        }
        __syncthreads();
    }
#pragma unroll
    for (int i2 = 0; i2 < 4; ++i2) {
        int gm = bm + tm + i2;
#pragma unroll
        for (int j2 = 0; j2 < 4; ++j2) {
            int gn = bn + tn + j2;
            if (gn < N) {
                float v = acc[i2][j2];
                if (BIAS) v += bias[gn];
                if (ACT == 1) v = (v > 0.f) ? v + log1pf(expf(-v)) : log1pf(expf(v));
                Y[(size_t)gm * N + gn] = v;
            }
        }
    }
}

// ---------------------------------------------------------------- layernorm (8192 rows x 128)
__global__ __launch_bounds__(256) void ln_kernel(
    const float* __restrict__ X, const float* __restrict__ g,
    const float* __restrict__ bb, float* __restrict__ Y)
{
    int row  = blockIdx.x * 4 + (threadIdx.x >> 6);
    int lane = threadIdx.x & 63;
    const float* xr = X + (size_t)row * 128;
    float v0 = xr[lane], v1 = xr[lane + 64];
    float s = v0 + v1;
#pragma unroll
    for (int off = 32; off > 0; off >>= 1) s += __shfl_xor(s, off, 64);
    float mean = s * 0.0078125f;
    float d0 = v0 - mean, d1 = v1 - mean;
    float q = d0 * d0 + d1 * d1;
#pragma unroll
    for (int off = 32; off > 0; off >>= 1) q += __shfl_xor(q, off, 64);
    float rstd = rsqrtf(q * 0.0078125f + 1e-5f);
    float* yr = Y + (size_t)row * 128;
    yr[lane]      = d0 * rstd * g[lane]      + bb[lane];
    yr[lane + 64] = d1 * rstd * g[lane + 64] + bb[lane + 64];
}

// ---------------------------------------------------------------- conv1d (depthwise causal k=4) + silu
__global__ __launch_bounds__(256) void conv_silu_kernel(
    const float* __restrict__ u, const float* __restrict__ cw,
    const float* __restrict__ cb, float* __restrict__ out)
{
    int i   = blockIdx.x * 256 + threadIdx.x;   // BLC * 64
    int dq  = (i & 63) << 2;
    int row = i >> 6;
    int l   = row & (LSEQ - 1);
    float4 a = *(const float4*)&cb[dq];
    float w[4][4];
#pragma unroll
    for (int e = 0; e < 4; ++e) {
        float4 we = *(const float4*)&cw[(dq + e) * 4];
        w[e][0] = we.x; w[e][1] = we.y; w[e][2] = we.z; w[e][3] = we.w;
    }
#pragma unroll
    for (int j = 0; j < 4; ++j) {
        if (l >= 3 - j) {
            const float4 v = *(const float4*)&u[(size_t)(row - 3 + j) * 256 + dq];
            a.x = fmaf(v.x, w[0][j], a.x);
            a.y = fmaf(v.y, w[1][j], a.y);
            a.z = fmaf(v.z, w[2][j], a.z);
            a.w = fmaf(v.w, w[3][j], a.w);
        }
    }
    float4 o;
    o.x = a.x / (1.f + __expf(-a.x));
    o.y = a.y / (1.f + __expf(-a.y));
    o.z = a.z / (1.f + __expf(-a.z));
    o.w = a.w / (1.f + __expf(-a.w));
    *(float4*)&out[(size_t)row * 256 + dq] = o;
}

// ---------------------------------------------------------------- chunked selective scan
// Lane owns 4 n-states of one d: g = tid&3 (n-quad), dloc = tid>>2 (64 d per block).
// grid (4, NC, B) = 512 blocks. B/C broadcast-loaded from dbl; dt/du float4-over-t.
__global__ __launch_bounds__(256) void scan_phase1(
    const float* __restrict__ dtT, const float* __restrict__ dtuT,
    const float* __restrict__ dbl, const float* __restrict__ A_log,
    float* __restrict__ hend, float* __restrict__ aprod)
{
    int g    = threadIdx.x & 3;
    int dloc = threadIdx.x >> 2;
    int d    = blockIdx.x * 64 + dloc;
    int c    = blockIdx.y;
    int b    = blockIdx.z;
    float4 al = *(const float4*)&A_log[d * 16 + g * 4];
    float A0 = -__expf(al.x), A1 = -__expf(al.y), A2 = -__expf(al.z), A3 = -__expf(al.w);
    int base = d * BLC + b * LSEQ + c * CHK;
    int row0 = b * LSEQ + c * CHK;
    float h0 = 0.f, h1 = 0.f, h2 = 0.f, h3 = 0.f;
    float p0 = 1.f, p1 = 1.f, p2 = 1.f, p3 = 1.f;
#pragma unroll 2
    for (int t4 = 0; t4 < CHK; t4 += 4) {
        float4 dt4 = *(const float4*)&dtT [base + t4];
        float4 du4 = *(const float4*)&dtuT[base + t4];
        float dts[4] = {dt4.x, dt4.y, dt4.z, dt4.w};
        float dus[4] = {du4.x, du4.y, du4.z, du4.w};
#pragma unroll
        for (int j = 0; j < 4; ++j) {
            float4 B4 = *(const float4*)&dbl[(size_t)(row0 + t4 + j) * 40 + 8 + g * 4];
            float a0 = __expf(dts[j] * A0), a1 = __expf(dts[j] * A1);
            float a2 = __expf(dts[j] * A2), a3 = __expf(dts[j] * A3);
            h0 = fmaf(a0, h0, dus[j] * B4.x); p0 *= a0;
            h1 = fmaf(a1, h1, dus[j] * B4.y); p1 *= a1;
            h2 = fmaf(a2, h2, dus[j] * B4.z); p2 *= a2;
            h3 = fmaf(a3, h3, dus[j] * B4.w); p3 *= a3;
        }
    }
    int ch = (b * 256 + d) * 16 + g * 4;
    *(float4*)&hend [c * NCH + ch] = make_float4(h0, h1, h2, h3);
    *(float4*)&aprod[c * NCH + ch] = make_float4(p0, p1, p2, p3);
}

// Serial prefix over chunks; h0 written in place of aprod. Coalesced [c][ch] layout.
__global__ __launch_bounds__(256) void scan_phase2(
    const float* __restrict__ hend, float* __restrict__ apr_h0)
{
    int ch = blockIdx.x * 256 + threadIdx.x;   // NCH
    float h = 0.f;
#pragma unroll
    for (int c = 0; c < NC; ++c) {
        float ap = apr_h0[c * NCH + ch];
        float he = hend[c * NCH + ch];
        apr_h0[c * NCH + ch] = h;
        h = fmaf(ap, h, he);
    }
}

// Phase 3: recompute from h0, dot with C (4 in-reg + 2 shuffles), write y[row][d].
__global__ __launch_bounds__(256) void scan_phase3(
    const float* __restrict__ dtT, const float* __restrict__ dtuT,
    const float* __restrict__ dbl, const float* __restrict__ A_log,
    const float* __restrict__ h0b, float* __restrict__ y)
{
    int g    = threadIdx.x & 3;
    int dloc = threadIdx.x >> 2;
    int d    = blockIdx.x * 64 + dloc;
    int c    = blockIdx.y;
    int b    = blockIdx.z;
    float4 al = *(const float4*)&A_log[d * 16 + g * 4];
    float A0 = -__expf(al.x), A1 = -__expf(al.y), A2 = -__expf(al.z), A3 = -__expf(al.w);
    int base = d * BLC + b * LSEQ + c * CHK;
    int row0 = b * LSEQ + c * CHK;
    int ch = (b * 256 + d) * 16 + g * 4;
    float4 hv = *(const float4*)&h0b[c * NCH + ch];
    float h0 = hv.x, h1 = hv.y, h2 = hv.z, h3 = hv.w;
#pragma unroll 2
    for (int t4 = 0; t4 < CHK; t4 += 4) {
        float4 dt4 = *(const float4*)&dtT [base + t4];
        float4 du4 = *(const float4*)&dtuT[base + t4];
        float dts[4] = {dt4.x, dt4.y, dt4.z, dt4.w};
        float dus[4] = {du4.x, du4.y, du4.z, du4.w};
#pragma unroll
        for (int j = 0; j < 4; ++j) {
            size_t rb = (size_t)(row0 + t4 + j) * 40;
            float4 B4 = *(const float4*)&dbl[rb + 8  + g * 4];
            float4 C4 = *(const float4*)&dbl[rb + 24 + g * 4];
            float a0 = __expf(dts[j] * A0), a1 = __expf(dts[j] * A1);
            float a2 = __expf(dts[j] * A2), a3 = __expf(dts[j] * A3);
            h0 = fmaf(a0, h0, dus[j] * B4.x);
            h1 = fmaf(a1, h1, dus[j] * B4.y);
            h2 = fmaf(a2, h2, dus[j] * B4.z);
            h3 = fmaf(a3, h3, dus[j] * B4.w);
            float p = h0 * C4.x;
            p = fmaf(h1, C4.y, p);
            p = fmaf(h2, C4.z, p);
            p = fmaf(h3, C4.w, p);
            p += __shfl_xor(p, 1);
            p += __shfl_xor(p, 2);
            if (g == 0) y[(size_t)(row0 + t4 + j) * 256 + d] = p;
        }
    }
}

// ---------------------------------------------------------------- launch
extern "C" void kernel_launch(void* const* d_in, const int* in_sizes, int n_in,
                              void* d_out, int out_size, void* d_ws, size_t ws_size,
                              hipStream_t stream)
{
    const float* x        = (const float*)d_in[0];
    const float* embed_w  = (const float*)d_in[1];
    const float* embed_b  = (const float*)d_in[2];
    const float* outc_w   = (const float*)d_in[3];
    const float* outc_b   = (const float*)d_in[4];
    const float* ln_g     = (const float*)d_in[5];
    const float* ln_b     = (const float*)d_in[6];
    const float* in_w     = (const float*)d_in[7];
    const float* conv_w   = (const float*)d_in[8];
    const float* conv_b   = (const float*)d_in[9];
    const float* xproj_w  = (const float*)d_in[10];
    const float* dtproj_w = (const float*)d_in[11];
    const float* dtproj_b = (const float*)d_in[12];
    const float* A_log    = (const float*)d_in[13];
    const float* ssm_D    = (const float*)d_in[14];
    const float* mout_w   = (const float*)d_in[15];
    const float* ffn_w1   = (const float*)d_in[16];
    const float* ffn_b1   = (const float*)d_in[17];
    const float* ffn_w2   = (const float*)d_in[18];
    const float* ffn_b2   = (const float*)d_in[19];

    float* ws   = (float*)d_ws;
    float* t    = ws;                   // (BLC,128)  1,048,576
    float* tmp2 = ws + 1048576;         // 2M: LN-out / dtuT
    float* ub   = ws + 3145728;         // 2M: in_proj u / dtT / ffn-mid lo
    float* zb   = ws + 5242880;         // 2M: in_proj z / ffn-mid hi
    float* ucv  = ws + 7340032;         // 2M: conv+silu out
    float* dtb  = ws + 9437184;         // 2M: dt -> y_scan
    float* dbl  = ws + 11534336;        // (BLC,40)   327,680
    float* hend = ws + 11862016;        // [NC][NCH]  524,288
    float* apr  = ws + 12386304;        // [NC][NCH]  524,288 -> h0
    float* out  = (float*)d_out;        // total 12,910,592 floats = 51.6 MB

    float* dtT    = ub;
    float* dtuT   = tmp2;
    float* ffnmid = ub;                 // spans ub+zb (BLC x 512)

    dim3 tb(32, 8);
    transpose_kernel<false><<<dim3(128, 4, 2), tb, 0, stream>>>(x, tmp2, nullptr, 128, 4096);
    mgemm<64, 0, true, false, false, false><<<dim3(128, 2), 256, 0, stream>>>(
        tmp2, embed_w, embed_b, nullptr, nullptr, nullptr, nullptr, t, nullptr, 128, 128);

    for (int i = 0; i < 2; ++i) {
        ln_kernel<<<2048, 256, 0, stream>>>(t, ln_g + i * 128, ln_b + i * 128, tmp2);
        mgemm<128, 0, false, false, true, false><<<dim3(64, 8), 256, 0, stream>>>(
            tmp2, in_w + i * 65536, nullptr, nullptr, nullptr, nullptr, nullptr, ub, zb, 512, 128);
        conv_silu_kernel<<<2048, 256, 0, stream>>>(ub, conv_w + i * 1024, conv_b + i * 256, ucv);
        gemm_kernel<0, false><<<dim3(128, 1), 256, 0, stream>>>(ucv, 256, xproj_w + i * 10240, nullptr, dbl, 40, 256);
        gemm_kernel<1, true><<<dim3(128, 4), 256, 0, stream>>>(dbl, 40, dtproj_w + i * 2048, dtproj_b + i * 256, dtb, 256, 8);
        transposeDT<<<dim3(8, 256), tb, 0, stream>>>(dtb, ucv, dtT, dtuT);
        scan_phase1<<<dim3(4, NC, 2), 256, 0, stream>>>(dtT, dtuT, dbl, A_log + i * 4096, hend, apr);
        scan_phase2<<<32, 256, 0, stream>>>(hend, apr);
        scan_phase3<<<dim3(4, NC, 2), 256, 0, stream>>>(dtT, dtuT, dbl, A_log + i * 4096, apr, dtb);
        mgemm<64, 0, false, true, false, true><<<dim3(128, 2), 256, 0, stream>>>(
            dtb, mout_w + i * 32768, nullptr, t, ucv, zb, ssm_D + i * 256, t, nullptr, 128, 256);
        ln_kernel<<<2048, 256, 0, stream>>>(t, ln_g + i * 128, ln_b + i * 128, tmp2);
        mgemm<128, 2, true, false, false, false><<<dim3(64, 8), 256, 0, stream>>>(
            tmp2, ffn_w1 + i * 65536, ffn_b1 + i * 512, nullptr, nullptr, nullptr, nullptr, ffnmid, nullptr, 512, 128);
        mgemm<64, 0, true, true, false, false><<<dim3(128, 2), 256, 0, stream>>>(
            ffnmid, ffn_w2 + i * 65536, ffn_b2 + i * 128, t, nullptr, nullptr, nullptr, t, nullptr, 128, 512);
    }

    mgemm<64, 0, true, false, false, false><<<dim3(128, 2), 256, 0, stream>>>(
        t, outc_w, outc_b, nullptr, nullptr, nullptr, nullptr, tmp2, nullptr, 128, 128);
    transpose_kernel<true><<<dim3(4, 128, 2), tb, 0, stream>>>(tmp2, out, x, 4096, 128);
}

// Round 8
// 427.422 us; speedup vs baseline: 1.9998x; 1.0553x over previous
//
#include <hip/hip_runtime.h>
#include <hip/hip_bf16.h>

// MambaFeatureEnhancer — B=2, C=128, L=4096, d_inner=256, N=16, R=8, 2 layers. All I/O fp32.
// All GEMMs bf16 MFMA (fp32 accum). dtproj folded into xproj via precomputed Wcomb;
// LN fused into in_proj/ffn1 staging; dt-GEMM writes transposed (dtT/dtuT) directly.

#define LSEQ 4096
#define BLC  8192      // B * L
#define NC   64        // scan chunks
#define CHK  64        // chunk length
#define NCH  8192      // B * d_inner * N state channels

typedef __attribute__((ext_vector_type(4))) float f32x4;
typedef __attribute__((ext_vector_type(8))) short s16x8;

__device__ __forceinline__ unsigned short f2bu(float f) {   // fp32 -> bf16 bits, RNE
    unsigned u = __float_as_uint(f);
    return (unsigned short)((u + 0x7fffu + ((u >> 16) & 1u)) >> 16);
}
__device__ __forceinline__ float softplus_f(float v) {
    return (v > 0.f) ? v + log1pf(expf(-v)) : log1pf(expf(v));
}

// ---------------------------------------------------------------- transpose (I/O reshape)
template<bool ADD>
__global__ __launch_bounds__(256) void transpose_kernel(
    const float* __restrict__ in_, float* __restrict__ out_,
    const float* __restrict__ add, int R, int Cc)
{
    __shared__ float tile[32][33];
    size_t boff = (size_t)blockIdx.z * R * Cc;
    int r0 = blockIdx.y * 32, c0 = blockIdx.x * 32;
    int tx = threadIdx.x, ty = threadIdx.y;   // block (32,8)
#pragma unroll
    for (int j = 0; j < 4; ++j)
        tile[ty + j * 8][tx] = in_[boff + (size_t)(r0 + ty + j * 8) * Cc + (c0 + tx)];
    __syncthreads();
#pragma unroll
    for (int j = 0; j < 4; ++j) {
        size_t idx = boff + (size_t)(c0 + ty + j * 8) * R + (r0 + tx);
        float v = tile[tx][ty + j * 8];
        if (ADD) v += add[idx];
        out_[idx] = v;
    }
}

// ---------------------------------------------------------------- Wcomb precompute
// wc[layer][row][k], row<256: sum_r dtproj_w[layer][row][r]*xproj_w[layer][r][k];
// row 256..287: xproj_w[layer][8+row-256][k]; row 288..319: 0.
__global__ __launch_bounds__(256) void build_wcomb(
    const float* __restrict__ xproj_w, const float* __restrict__ dtproj_w,
    float* __restrict__ wc)
{
    int i = blockIdx.x * 256 + threadIdx.x;     // 0 .. 2*320*256-1
    int layer = i / 81920;
    int rem   = i - layer * 81920;
    int row = rem >> 8, col = rem & 255;
    const float* xp = xproj_w + layer * 10240;
    float v = 0.f;
    if (row < 256) {
        const float* dw = dtproj_w + layer * 2048 + row * 8;
#pragma unroll
        for (int r = 0; r < 8; ++r) v = fmaf(dw[r], xp[r * 256 + col], v);
    } else if (row < 288) {
        v = xp[(8 + row - 256) * 256 + col];
    }
    wc[i] = v;
}

// ---------------------------------------------------------------- bf16 MFMA GEMM (generic)
// Y[m,n] = act( sum_k X[m,k]*W[n,k] + bias[n] ) (+ res[m,n]). BM in {64,128}, BN=64.
// EPI (K=256): X[m,k] := (X[m,k] + pu[m,k]*pD[k]) * silu(pz[m,k]) during staging.
template<int BM, int ACT, bool BIAS, bool RES, bool EPI>
__global__ __launch_bounds__(256) void mgemm(
    const float* __restrict__ X, const float* __restrict__ W,
    const float* __restrict__ bias, const float* __restrict__ res,
    const float* __restrict__ pu, const float* __restrict__ pz,
    const float* __restrict__ pD,
    float* __restrict__ Y, int N, int K)
{
    constexpr int MF = BM / 32;
    __shared__ __align__(16) unsigned short Xs[BM * 64];
    __shared__ __align__(16) unsigned short Ws[64 * 64];
    int tid  = threadIdx.x;
    int lane = tid & 63;
    int wave = tid >> 6;
    int wm = wave >> 1, wn = wave & 1;
    int l15 = lane & 15, l4 = lane >> 4;
    int bm = blockIdx.x * BM, bn = blockIdx.y * 64;
    f32x4 acc[MF][2] = {};
    int q  = tid & 15;
    int r0 = tid >> 4;

    for (int k0 = 0; k0 < K; k0 += 64) {
        __syncthreads();
#pragma unroll
        for (int p = 0; p < BM / 16; ++p) {
            int row = r0 + p * 16;
            size_t gi = (size_t)(bm + row) * K + k0 + q * 4;
            float4 v = *(const float4*)&X[gi];
            if (EPI) {
                float4 u4 = *(const float4*)&pu[gi];
                float4 z4 = *(const float4*)&pz[gi];
                float4 D4 = *(const float4*)&pD[k0 + q * 4];
                v.x = fmaf(u4.x, D4.x, v.x) * (z4.x / (1.f + __expf(-z4.x)));
                v.y = fmaf(u4.y, D4.y, v.y) * (z4.y / (1.f + __expf(-z4.y)));
                v.z = fmaf(u4.z, D4.z, v.z) * (z4.z / (1.f + __expf(-z4.z)));
                v.w = fmaf(u4.w, D4.w, v.w) * (z4.w / (1.f + __expf(-z4.w)));
            }
            unsigned lo = f2bu(v.x) | ((unsigned)f2bu(v.y) << 16);
            unsigned hi = f2bu(v.z) | ((unsigned)f2bu(v.w) << 16);
            int off = (row * 128 + q * 8) ^ ((row & 7) << 4);
            *(uint2*)((char*)Xs + off) = make_uint2(lo, hi);
        }
#pragma unroll
        for (int p = 0; p < 4; ++p) {
            int row = r0 + p * 16;
            float4 v = *(const float4*)&W[(size_t)(bn + row) * K + k0 + q * 4];
            unsigned lo = f2bu(v.x) | ((unsigned)f2bu(v.y) << 16);
            unsigned hi = f2bu(v.z) | ((unsigned)f2bu(v.w) << 16);
            int off = (row * 128 + q * 8) ^ ((row & 7) << 4);
            *(uint2*)((char*)Ws + off) = make_uint2(lo, hi);
        }
        __syncthreads();
#pragma unroll
        for (int ks = 0; ks < 2; ++ks) {
            s16x8 a[MF], b[2];
#pragma unroll
            for (int mf = 0; mf < MF; ++mf) {
                int row = wm * (BM / 2) + mf * 16 + l15;
                int off = (row * 128 + (ks * 32 + l4 * 8) * 2) ^ ((row & 7) << 4);
                a[mf] = *(const s16x8*)((const char*)Xs + off);
            }
#pragma unroll
            for (int nf = 0; nf < 2; ++nf) {
                int row = wn * 32 + nf * 16 + l15;
                int off = (row * 128 + (ks * 32 + l4 * 8) * 2) ^ ((row & 7) << 4);
                b[nf] = *(const s16x8*)((const char*)Ws + off);
            }
#pragma unroll
            for (int mf = 0; mf < MF; ++mf)
#pragma unroll
                for (int nf = 0; nf < 2; ++nf)
                    acc[mf][nf] = __builtin_amdgcn_mfma_f32_16x16x32_bf16(
                        a[mf], b[nf], acc[mf][nf], 0, 0, 0);
        }
    }

#pragma unroll
    for (int mf = 0; mf < MF; ++mf) {
#pragma unroll
        for (int nf = 0; nf < 2; ++nf) {
            int col   = bn + wn * 32 + nf * 16 + l15;
            int rbase = bm + wm * (BM / 2) + mf * 16 + l4 * 4;
            float bv = BIAS ? bias[col] : 0.f;
#pragma unroll
            for (int r = 0; r < 4; ++r) {
                float v = acc[mf][nf][r] + bv;
                if (ACT == 2) v = 0.5f * v * (1.f + erff(v * 0.70710678118654752f));
                size_t o = (size_t)(rbase + r) * N + col;
                if (RES) v += res[o];
                Y[o] = v;
            }
        }
    }
}

// ---------------------------------------------------------------- LN-fused GEMM (BM=128, K=128)
// X = t (BLC x 128); LN per row fused into bf16 staging. SPLIT: N=512 -> Y(0..255)/Y2(256..511).
template<int ACT, bool BIAS, bool SPLIT>
__global__ __launch_bounds__(256) void mgemm_ln(
    const float* __restrict__ X,
    const float* __restrict__ lng, const float* __restrict__ lnb,
    const float* __restrict__ W, const float* __restrict__ bias,
    float* __restrict__ Y, float* __restrict__ Y2, int N)
{
    __shared__ __align__(16) unsigned short Xs[128 * 128];   // 32 KB, full K staged
    __shared__ __align__(16) unsigned short Ws[64 * 64];
    int tid  = threadIdx.x;
    int lane = tid & 63;
    int wave = tid >> 6;
    int wm = wave >> 1, wn = wave & 1;
    int l15 = lane & 15, l4 = lane >> 4;
    int bm = blockIdx.x * 128, bn = blockIdx.y * 64;

    // ---- LN + quantize X tile (128 rows x 128 cols)
    int rsub = lane >> 4;   // 0..3
    int cg   = lane & 15;   // 0..15, 8 cols each
    float4 ga = *(const float4*)&lng[cg * 8], gb = *(const float4*)&lng[cg * 8 + 4];
    float4 ba = *(const float4*)&lnb[cg * 8], bb2 = *(const float4*)&lnb[cg * 8 + 4];
#pragma unroll 2
    for (int it = 0; it < 8; ++it) {
        int row = wave * 32 + it * 4 + rsub;
        const float* xr = X + (size_t)(bm + row) * 128 + cg * 8;
        float4 xa = *(const float4*)xr;
        float4 xb = *(const float4*)(xr + 4);
        float s = xa.x + xa.y + xa.z + xa.w + xb.x + xb.y + xb.z + xb.w;
        float q = xa.x*xa.x + xa.y*xa.y + xa.z*xa.z + xa.w*xa.w
                + xb.x*xb.x + xb.y*xb.y + xb.z*xb.z + xb.w*xb.w;
        s += __shfl_xor(s, 1, 16); q += __shfl_xor(q, 1, 16);
        s += __shfl_xor(s, 2, 16); q += __shfl_xor(q, 2, 16);
        s += __shfl_xor(s, 4, 16); q += __shfl_xor(q, 4, 16);
        s += __shfl_xor(s, 8, 16); q += __shfl_xor(q, 8, 16);
        float mean = s * 0.0078125f;
        float var  = fmaf(-mean, mean, q * 0.0078125f);
        float rstd = rsqrtf(var + 1e-5f);
        float o0 = fmaf((xa.x - mean) * rstd, ga.x, ba.x);
        float o1 = fmaf((xa.y - mean) * rstd, ga.y, ba.y);
        float o2 = fmaf((xa.z - mean) * rstd, ga.z, ba.z);
        float o3 = fmaf((xa.w - mean) * rstd, ga.w, ba.w);
        float o4 = fmaf((xb.x - mean) * rstd, gb.x, bb2.x);
        float o5 = fmaf((xb.y - mean) * rstd, gb.y, bb2.y);
        float o6 = fmaf((xb.z - mean) * rstd, gb.z, bb2.z);
        float o7 = fmaf((xb.w - mean) * rstd, gb.w, bb2.w);
        uint4 wv;
        wv.x = f2bu(o0) | ((unsigned)f2bu(o1) << 16);
        wv.y = f2bu(o2) | ((unsigned)f2bu(o3) << 16);
        wv.z = f2bu(o4) | ((unsigned)f2bu(o5) << 16);
        wv.w = f2bu(o6) | ((unsigned)f2bu(o7) << 16);
        int off = (row * 256 + cg * 16) ^ ((row & 7) << 4);
        *(uint4*)((char*)Xs + off) = wv;
    }

    f32x4 acc[4][2] = {};
    int q4 = tid & 15, r0 = tid >> 4;
    for (int k0 = 0; k0 < 128; k0 += 64) {
#pragma unroll
        for (int p = 0; p < 4; ++p) {
            int row = r0 + p * 16;
            float4 v = *(const float4*)&W[(size_t)(bn + row) * 128 + k0 + q4 * 4];
            unsigned lo = f2bu(v.x) | ((unsigned)f2bu(v.y) << 16);
            unsigned hi = f2bu(v.z) | ((unsigned)f2bu(v.w) << 16);
            int off = (row * 128 + q4 * 8) ^ ((row & 7) << 4);
            *(uint2*)((char*)Ws + off) = make_uint2(lo, hi);
        }
        __syncthreads();
#pragma unroll
        for (int ks = 0; ks < 2; ++ks) {
            s16x8 a[4], b[2];
#pragma unroll
            for (int mf = 0; mf < 4; ++mf) {
                int row = wm * 64 + mf * 16 + l15;
                int off = (row * 256 + (k0 + ks * 32 + l4 * 8) * 2) ^ ((row & 7) << 4);
                a[mf] = *(const s16x8*)((const char*)Xs + off);
            }
#pragma unroll
            for (int nf = 0; nf < 2; ++nf) {
                int row = wn * 32 + nf * 16 + l15;
                int off = (row * 128 + (ks * 32 + l4 * 8) * 2) ^ ((row & 7) << 4);
                b[nf] = *(const s16x8*)((const char*)Ws + off);
            }
#pragma unroll
            for (int mf = 0; mf < 4; ++mf)
#pragma unroll
                for (int nf = 0; nf < 2; ++nf)
                    acc[mf][nf] = __builtin_amdgcn_mfma_f32_16x16x32_bf16(
                        a[mf], b[nf], acc[mf][nf], 0, 0, 0);
        }
        __syncthreads();
    }

#pragma unroll
    for (int mf = 0; mf < 4; ++mf) {
#pragma unroll
        for (int nf = 0; nf < 2; ++nf) {
            int col   = bn + wn * 32 + nf * 16 + l15;
            int rbase = bm + wm * 64 + mf * 16 + l4 * 4;
            float bv = BIAS ? bias[col] : 0.f;
#pragma unroll
            for (int r = 0; r < 4; ++r) {
                float v = acc[mf][nf][r] + bv;
                if (ACT == 2) v = 0.5f * v * (1.f + erff(v * 0.70710678118654752f));
                if (SPLIT) {
                    if (col < 256) Y [(size_t)(rbase + r) * 256 + col]       = v;
                    else           Y2[(size_t)(rbase + r) * 256 + col - 256] = v;
                } else {
                    Y[(size_t)(rbase + r) * N + col] = v;
                }
            }
        }
    }
}

// ---------------------------------------------------------------- dt+B/C GEMM (BM=128, K=256, N=320)
// X = ucv; W = Wcomb. Blocks bn<256: dt = softplus(acc+bias) -> dtT[d][row], dtuT = dt*u.
// Block bn==256: cols 0..31 -> bct[n][row] (B rows 0..15, C rows 16..31).
__global__ __launch_bounds__(256) void mgemm_dtbc(
    const float* __restrict__ Xu, const float* __restrict__ W,
    const float* __restrict__ bias,
    float* __restrict__ dtT, float* __restrict__ dtuT, float* __restrict__ bct)
{
    __shared__ __align__(16) unsigned short Xs[128 * 64];
    __shared__ __align__(16) unsigned short Ws[64 * 64];
    int tid  = threadIdx.x;
    int lane = tid & 63;
    int wave = tid >> 6;
    int wm = wave >> 1, wn = wave & 1;
    int l15 = lane & 15, l4 = lane >> 4;
    int bm = blockIdx.x * 128, bn = blockIdx.y * 64;
    f32x4 acc[4][2] = {};
    int q  = tid & 15;
    int r0 = tid >> 4;

    for (int k0 = 0; k0 < 256; k0 += 64) {
        __syncthreads();
#pragma unroll
        for (int p = 0; p < 8; ++p) {
            int row = r0 + p * 16;
            float4 v = *(const float4*)&Xu[(size_t)(bm + row) * 256 + k0 + q * 4];
            unsigned lo = f2bu(v.x) | ((unsigned)f2bu(v.y) << 16);
            unsigned hi = f2bu(v.z) | ((unsigned)f2bu(v.w) << 16);
            int off = (row * 128 + q * 8) ^ ((row & 7) << 4);
            *(uint2*)((char*)Xs + off) = make_uint2(lo, hi);
        }
#pragma unroll
        for (int p = 0; p < 4; ++p) {
            int row = r0 + p * 16;
            float4 v = *(const float4*)&W[(size_t)(bn + row) * 256 + k0 + q * 4];
            unsigned lo = f2bu(v.x) | ((unsigned)f2bu(v.y) << 16);
            unsigned hi = f2bu(v.z) | ((unsigned)f2bu(v.w) << 16);
            int off = (row * 128 + q * 8) ^ ((row & 7) << 4);
            *(uint2*)((char*)Ws + off) = make_uint2(lo, hi);
        }
        __syncthreads();
#pragma unroll
        for (int ks = 0; ks < 2; ++ks) {
            s16x8 a[4], b[2];
#pragma unroll
            for (int mf = 0; mf < 4; ++mf) {
                int row = wm * 64 + mf * 16 + l15;
                int off = (row * 128 + (ks * 32 + l4 * 8) * 2) ^ ((row & 7) << 4);
                a[mf] = *(const s16x8*)((const char*)Xs + off);
            }
#pragma unroll
            for (int nf = 0; nf < 2; ++nf) {
                int row = wn * 32 + nf * 16 + l15;
                int off = (row * 128 + (ks * 32 + l4 * 8) * 2) ^ ((row & 7) << 4);
                b[nf] = *(const s16x8*)((const char*)Ws + off);
            }
#pragma unroll
            for (int mf = 0; mf < 4; ++mf)
#pragma unroll
                for (int nf = 0; nf < 2; ++nf)
                    acc[mf][nf] = __builtin_amdgcn_mfma_f32_16x16x32_bf16(
                        a[mf], b[nf], acc[mf][nf], 0, 0, 0);
        }
    }

    if (bn < 256) {
#pragma unroll
        for (int mf = 0; mf < 4; ++mf) {
#pragma unroll
            for (int nf = 0; nf < 2; ++nf) {
                int col   = bn + wn * 32 + nf * 16 + l15;
                int rbase = bm + wm * 64 + mf * 16 + l4 * 4;
                float bv = bias[col];
                float4 uu;
                uu.x = Xu[(size_t)(rbase + 0) * 256 + col];
                uu.y = Xu[(size_t)(rbase + 1) * 256 + col];
                uu.z = Xu[(size_t)(rbase + 2) * 256 + col];
                uu.w = Xu[(size_t)(rbase + 3) * 256 + col];
                float4 dtv, duv;
                float v0 = softplus_f(acc[mf][nf][0] + bv);
                float v1 = softplus_f(acc[mf][nf][1] + bv);
                float v2 = softplus_f(acc[mf][nf][2] + bv);
                float v3 = softplus_f(acc[mf][nf][3] + bv);
                dtv = make_float4(v0, v1, v2, v3);
                duv = make_float4(v0 * uu.x, v1 * uu.y, v2 * uu.z, v3 * uu.w);
                *(float4*)&dtT [(size_t)col * BLC + rbase] = dtv;
                *(float4*)&dtuT[(size_t)col * BLC + rbase] = duv;
            }
        }
    } else {
#pragma unroll
        for (int mf = 0; mf < 4; ++mf) {
#pragma unroll
            for (int nf = 0; nf < 2; ++nf) {
                int col16 = wn * 32 + nf * 16 + l15;     // 0..63, valid < 32
                int rbase = bm + wm * 64 + mf * 16 + l4 * 4;
                if (col16 < 32) {
                    float4 v = make_float4(acc[mf][nf][0], acc[mf][nf][1],
                                           acc[mf][nf][2], acc[mf][nf][3]);
                    *(float4*)&bct[(size_t)col16 * BLC + rbase] = v;
                }
            }
        }
    }
}

// ---------------------------------------------------------------- conv1d (depthwise causal k=4) + silu
__global__ __launch_bounds__(256) void conv_silu_kernel(
    const float* __restrict__ u, const float* __restrict__ cw,
    const float* __restrict__ cb, float* __restrict__ out)
{
    int i   = blockIdx.x * 256 + threadIdx.x;   // BLC * 64
    int dq  = (i & 63) << 2;
    int row = i >> 6;
    int l   = row & (LSEQ - 1);
    float4 a = *(const float4*)&cb[dq];
    float w[4][4];
#pragma unroll
    for (int e = 0; e < 4; ++e) {
        float4 we = *(const float4*)&cw[(dq + e) * 4];
        w[e][0] = we.x; w[e][1] = we.y; w[e][2] = we.z; w[e][3] = we.w;
    }
#pragma unroll
    for (int j = 0; j < 4; ++j) {
        if (l >= 3 - j) {
            const float4 v = *(const float4*)&u[(size_t)(row - 3 + j) * 256 + dq];
            a.x = fmaf(v.x, w[0][j], a.x);
            a.y = fmaf(v.y, w[1][j], a.y);
            a.z = fmaf(v.z, w[2][j], a.z);
            a.w = fmaf(v.w, w[3][j], a.w);
        }
    }
    float4 o;
    o.x = a.x / (1.f + __expf(-a.x));
    o.y = a.y / (1.f + __expf(-a.y));
    o.z = a.z / (1.f + __expf(-a.z));
    o.w = a.w / (1.f + __expf(-a.w));
    *(float4*)&out[(size_t)row * 256 + dq] = o;
}

// ---------------------------------------------------------------- chunked selective scan
// Lane owns 4 n-states of one d: g = tid&3, dloc = tid>>2. grid (4, NC, B).
__global__ __launch_bounds__(256) void scan_phase1(
    const float* __restrict__ dtT, const float* __restrict__ dtuT,
    const float* __restrict__ bct, const float* __restrict__ A_log,
    float* __restrict__ hend, float* __restrict__ aprod)
{
    int g    = threadIdx.x & 3;
    int dloc = threadIdx.x >> 2;
    int d    = blockIdx.x * 64 + dloc;
    int c    = blockIdx.y;
    int b    = blockIdx.z;
    float4 al = *(const float4*)&A_log[d * 16 + g * 4];
    float A0 = -__expf(al.x), A1 = -__expf(al.y), A2 = -__expf(al.z), A3 = -__expf(al.w);
    int base   = d * BLC + b * LSEQ + c * CHK;
    int btbase = b * LSEQ + c * CHK;
    const float* B0p = bct + (size_t)(g * 4 + 0) * BLC + btbase;
    const float* B1p = B0p + BLC;
    const float* B2p = B1p + BLC;
    const float* B3p = B2p + BLC;
    float h0 = 0.f, h1 = 0.f, h2 = 0.f, h3 = 0.f;
    float p0 = 1.f, p1 = 1.f, p2 = 1.f, p3 = 1.f;
#pragma unroll 2
    for (int t4 = 0; t4 < CHK; t4 += 4) {
        float4 dt4 = *(const float4*)&dtT [base + t4];
        float4 du4 = *(const float4*)&dtuT[base + t4];
        float4 B0 = *(const float4*)(B0p + t4);
        float4 B1 = *(const float4*)(B1p + t4);
        float4 B2 = *(const float4*)(B2p + t4);
        float4 B3 = *(const float4*)(B3p + t4);
        float dts[4] = {dt4.x, dt4.y, dt4.z, dt4.w};
        float dus[4] = {du4.x, du4.y, du4.z, du4.w};
        float b0[4] = {B0.x, B0.y, B0.z, B0.w};
        float b1[4] = {B1.x, B1.y, B1.z, B1.w};
        float b2[4] = {B2.x, B2.y, B2.z, B2.w};
        float b3[4] = {B3.x, B3.y, B3.z, B3.w};
#pragma unroll
        for (int j = 0; j < 4; ++j) {
            float a0 = __expf(dts[j] * A0), a1 = __expf(dts[j] * A1);
            float a2 = __expf(dts[j] * A2), a3 = __expf(dts[j] * A3);
            h0 = fmaf(a0, h0, dus[j] * b0[j]); p0 *= a0;
            h1 = fmaf(a1, h1, dus[j] * b1[j]); p1 *= a1;
            h2 = fmaf(a2, h2, dus[j] * b2[j]); p2 *= a2;
            h3 = fmaf(a3, h3, dus[j] * b3[j]); p3 *= a3;
        }
    }
    int ch = (b * 256 + d) * 16 + g * 4;
    *(float4*)&hend [c * NCH + ch] = make_float4(h0, h1, h2, h3);
    *(float4*)&aprod[c * NCH + ch] = make_float4(p0, p1, p2, p3);
}

__global__ __launch_bounds__(256) void scan_phase2(
    const float* __restrict__ hend, float* __restrict__ apr_h0)
{
    int ch = blockIdx.x * 256 + threadIdx.x;   // NCH
    float h = 0.f;
#pragma unroll
    for (int c = 0; c < NC; ++c) {
        float ap = apr_h0[c * NCH + ch];
        float he = hend[c * NCH + ch];
        apr_h0[c * NCH + ch] = h;
        h = fmaf(ap, h, he);
    }
}

__global__ __launch_bounds__(256) void scan_phase3(
    const float* __restrict__ dtT, const float* __restrict__ dtuT,
    const float* __restrict__ bct, const float* __restrict__ A_log,
    const float* __restrict__ h0b, float* __restrict__ y)
{
    int g    = threadIdx.x & 3;
    int dloc = threadIdx.x >> 2;
    int d    = blockIdx.x * 64 + dloc;
    int c    = blockIdx.y;
    int b    = blockIdx.z;
    float4 al = *(const float4*)&A_log[d * 16 + g * 4];
    float A0 = -__expf(al.x), A1 = -__expf(al.y), A2 = -__expf(al.z), A3 = -__expf(al.w);
    int base   = d * BLC + b * LSEQ + c * CHK;
    int row0   = b * LSEQ + c * CHK;
    const float* B0p = bct + (size_t)(g * 4 + 0) * BLC + row0;
    const float* B1p = B0p + BLC;
    const float* B2p = B1p + BLC;
    const float* B3p = B2p + BLC;
    const float* C0p = bct + (size_t)(16 + g * 4) * BLC + row0;
    const float* C1p = C0p + BLC;
    const float* C2p = C1p + BLC;
    const float* C3p = C2p + BLC;
    int ch = (b * 256 + d) * 16 + g * 4;
    float4 hv = *(const float4*)&h0b[c * NCH + ch];
    float h0 = hv.x, h1 = hv.y, h2 = hv.z, h3 = hv.w;
#pragma unroll 2
    for (int t4 = 0; t4 < CHK; t4 += 4) {
        float4 dt4 = *(const float4*)&dtT [base + t4];
        float4 du4 = *(const float4*)&dtuT[base + t4];
        float4 B0 = *(const float4*)(B0p + t4);
        float4 B1 = *(const float4*)(B1p + t4);
        float4 B2 = *(const float4*)(B2p + t4);
        float4 B3 = *(const float4*)(B3p + t4);
        float4 C0 = *(const float4*)(C0p + t4);
        float4 C1 = *(const float4*)(C1p + t4);
        float4 C2 = *(const float4*)(C2p + t4);
        float4 C3 = *(const float4*)(C3p + t4);
        float dts[4] = {dt4.x, dt4.y, dt4.z, dt4.w};
        float dus[4] = {du4.x, du4.y, du4.z, du4.w};
        float b0[4] = {B0.x, B0.y, B0.z, B0.w};
        float b1[4] = {B1.x, B1.y, B1.z, B1.w};
        float b2[4] = {B2.x, B2.y, B2.z, B2.w};
        float b3[4] = {B3.x, B3.y, B3.z, B3.w};
        float c0[4] = {C0.x, C0.y, C0.z, C0.w};
        float c1[4] = {C1.x, C1.y, C1.z, C1.w};
        float c2[4] = {C2.x, C2.y, C2.z, C2.w};
        float c3[4] = {C3.x, C3.y, C3.z, C3.w};
#pragma unroll
        for (int j = 0; j < 4; ++j) {
            float a0 = __expf(dts[j] * A0), a1 = __expf(dts[j] * A1);
            float a2 = __expf(dts[j] * A2), a3 = __expf(dts[j] * A3);
            h0 = fmaf(a0, h0, dus[j] * b0[j]);
            h1 = fmaf(a1, h1, dus[j] * b1[j]);
            h2 = fmaf(a2, h2, dus[j] * b2[j]);
            h3 = fmaf(a3, h3, dus[j] * b3[j]);
            float p = h0 * c0[j];
            p = fmaf(h1, c1[j], p);
            p = fmaf(h2, c2[j], p);
            p = fmaf(h3, c3[j], p);
            p += __shfl_xor(p, 1);
            p += __shfl_xor(p, 2);
            if (g == 0) y[(size_t)(row0 + t4 + j) * 256 + d] = p;
        }
    }
}

// ---------------------------------------------------------------- launch
extern "C" void kernel_launch(void* const* d_in, const int* in_sizes, int n_in,
                              void* d_out, int out_size, void* d_ws, size_t ws_size,
                              hipStream_t stream)
{
    const float* x        = (const float*)d_in[0];
    const float* embed_w  = (const float*)d_in[1];
    const float* embed_b  = (const float*)d_in[2];
    const float* outc_w   = (const float*)d_in[3];
    const float* outc_b   = (const float*)d_in[4];
    const float* ln_g     = (const float*)d_in[5];
    const float* ln_b     = (const float*)d_in[6];
    const float* in_w     = (const float*)d_in[7];
    const float* conv_w   = (const float*)d_in[8];
    const float* conv_b   = (const float*)d_in[9];
    const float* xproj_w  = (const float*)d_in[10];
    const float* dtproj_w = (const float*)d_in[11];
    const float* dtproj_b = (const float*)d_in[12];
    const float* A_log    = (const float*)d_in[13];
    const float* ssm_D    = (const float*)d_in[14];
    const float* mout_w   = (const float*)d_in[15];
    const float* ffn_w1   = (const float*)d_in[16];
    const float* ffn_b1   = (const float*)d_in[17];
    const float* ffn_w2   = (const float*)d_in[18];
    const float* ffn_b2   = (const float*)d_in[19];

    float* ws    = (float*)d_ws;
    float* t     = ws;                  // (BLC,128)  1,048,576
    float* tmp2  = ws + 1048576;        // 2M: transpose-in out / dtuT / outc out
    float* ub    = ws + 3145728;        // 2M: u / dtT / ffn-mid lo
    float* zb    = ws + 5242880;        // 2M: z / ffn-mid hi
    float* ucv   = ws + 7340032;        // 2M: conv+silu out
    float* dtb   = ws + 9437184;        // 2M: y_scan
    float* bct   = ws + 11534336;       // [32][BLC]  262,144
    float* hend  = ws + 11796480;       // [NC][NCH]  524,288
    float* apr   = ws + 12320768;       // [NC][NCH]  524,288 -> h0
    float* wcomb = ws + 12845056;       // 2 x 320 x 256 = 163,840  (total 13,008,896 = 52 MB)
    float* out   = (float*)d_out;

    float* dtT    = ub;
    float* dtuT   = tmp2;
    float* ffnmid = ub;                 // spans ub+zb (BLC x 512)

    dim3 tb(32, 8);
    build_wcomb<<<640, 256, 0, stream>>>(xproj_w, dtproj_w, wcomb);
    transpose_kernel<false><<<dim3(128, 4, 2), tb, 0, stream>>>(x, tmp2, nullptr, 128, 4096);
    mgemm<64, 0, true, false, false><<<dim3(128, 2), 256, 0, stream>>>(
        tmp2, embed_w, embed_b, nullptr, nullptr, nullptr, nullptr, t, 128, 128);

    for (int i = 0; i < 2; ++i) {
        mgemm_ln<0, false, true><<<dim3(64, 8), 256, 0, stream>>>(
            t, ln_g + i * 128, ln_b + i * 128, in_w + i * 65536, nullptr, ub, zb, 512);
        conv_silu_kernel<<<2048, 256, 0, stream>>>(ub, conv_w + i * 1024, conv_b + i * 256, ucv);
        mgemm_dtbc<<<dim3(64, 5), 256, 0, stream>>>(
            ucv, wcomb + i * 81920, dtproj_b + i * 256, dtT, dtuT, bct);
        scan_phase1<<<dim3(4, NC, 2), 256, 0, stream>>>(dtT, dtuT, bct, A_log + i * 4096, hend, apr);
        scan_phase2<<<32, 256, 0, stream>>>(hend, apr);
        scan_phase3<<<dim3(4, NC, 2), 256, 0, stream>>>(dtT, dtuT, bct, A_log + i * 4096, apr, dtb);
        mgemm<64, 0, false, true, true><<<dim3(128, 2), 256, 0, stream>>>(
            dtb, mout_w + i * 32768, nullptr, t, ucv, zb, ssm_D + i * 256, t, 128, 256);
        mgemm_ln<2, true, false><<<dim3(64, 8), 256, 0, stream>>>(
            t, ln_g + i * 128, ln_b + i * 128, ffn_w1 + i * 65536, ffn_b1 + i * 512, ffnmid, nullptr, 512);
        mgemm<64, 0, true, true, false><<<dim3(128, 2), 256, 0, stream>>>(
            ffnmid, ffn_w2 + i * 65536, ffn_b2 + i * 128, t, nullptr, nullptr, nullptr, t, 128, 512);
    }

    mgemm<64, 0, true, false, false><<<dim3(128, 2), 256, 0, stream>>>(
        t, outc_w, outc_b, nullptr, nullptr, nullptr, nullptr, tmp2, 128, 128);
    transpose_kernel<true><<<dim3(4, 128, 2), tb, 0, stream>>>(tmp2, out, x, 4096, 128);
}